// Round 1
// baseline (264.413 us; speedup 1.0000x reference)
//
#include <hip/hip_runtime.h>
#include <math.h>

#define PIX 4096        // 64*64 pixels
#define NQKV 192
#define MKEYS 147456    // 9216*16 per head

// ws layout in floats
#define OFF_QKV 0
#define OFF_KK  786432                    // 192*4096
#define OFF_VV  (786432 + 589824)
#define OFF_AO  (786432 + 2*589824)       // attn out [64][4096]

// ---------------- K1: norm + qkv projection ----------------
// grid 128 (32 pixels each), block 256
__global__ __launch_bounds__(256)
void k_norm_qkv(const float* __restrict__ x, const float* __restrict__ w_qkv,
                const float* __restrict__ ln_w, float* __restrict__ qkv)
{
    __shared__ float xs[64 * 32];    // xs[c][pl], c-major
    __shared__ float ws[192 * 64];   // ws[o][c]
    __shared__ float rs[32];
    const int tid = threadIdx.x;
    const int pbase = blockIdx.x * 32;

    for (int idx = tid; idx < 2048; idx += 256) {
        int c = idx >> 5, pl = idx & 31;
        xs[idx] = x[c * PIX + pbase + pl];
    }
    for (int idx = tid; idx < 192 * 64; idx += 256) ws[idx] = w_qkv[idx];
    __syncthreads();

    if (tid < 32) {
        float s = 0.f, s2 = 0.f;
        #pragma unroll
        for (int c = 0; c < 64; ++c) {
            float v = xs[c * 32 + tid];
            s += v; s2 = fmaf(v, v, s2);
        }
        float mean = s * 0.015625f;
        float var  = fmaf(-mean, mean, s2 * 0.015625f);
        rs[tid] = 1.0f / sqrtf(var + 1e-5f);
    }
    __syncthreads();
    for (int idx = tid; idx < 2048; idx += 256) {
        int c = idx >> 5, pl = idx & 31;
        xs[idx] *= rs[pl] * ln_w[c];
    }
    __syncthreads();

    // thread: pl = tid&31, og = tid>>5 (0..7) -> 24 outputs each
    const int pl = tid & 31;
    const int og = tid >> 5;
    float accs[24];
    #pragma unroll
    for (int j = 0; j < 24; ++j) accs[j] = 0.f;

    for (int c4 = 0; c4 < 64; c4 += 4) {
        float xv0 = xs[(c4 + 0) * 32 + pl];
        float xv1 = xs[(c4 + 1) * 32 + pl];
        float xv2 = xs[(c4 + 2) * 32 + pl];
        float xv3 = xs[(c4 + 3) * 32 + pl];
        #pragma unroll
        for (int j = 0; j < 24; ++j) {
            const float4 w4 = *(const float4*)&ws[(og * 24 + j) * 64 + c4];
            accs[j] = fmaf(xv0, w4.x, fmaf(xv1, w4.y, fmaf(xv2, w4.z, fmaf(xv3, w4.w, accs[j]))));
        }
    }
    #pragma unroll
    for (int j = 0; j < 24; ++j)
        qkv[(og * 24 + j) * PIX + pbase + pl] = accs[j];
}

// ---------------- K2: unfold gather -> KK, VV ----------------
// one thread per (head,m,d) element; grid 2304, block 256
__global__ __launch_bounds__(256)
void k_unfold(const float* __restrict__ qkv, float* __restrict__ KK, float* __restrict__ VV)
{
    const int idx = blockIdx.x * 256 + threadIdx.x;   // < 589824
    const int h = idx / MKEYS;
    const int r = idx - h * MKEYS;
    const int m = r >> 4;
    const int d = r & 15;
    const int cc  = m / 576;
    const int r2  = m - cc * 576;
    const int orr = r2 / 48;
    const int r3  = r2 - orr * 48;
    const int oc  = r3 >> 2;
    const int wg  = r3 & 3;
    const int row = wg * 16 + (d >> 3) * 8 + orr - 2;
    const int col = (d & 7) * 8 + oc - 2;
    const int c   = h * 16 + cc;
    const bool ok = ((unsigned)row < 64u) && ((unsigned)col < 64u);
    const int src = row * 64 + col;
    KK[idx] = ok ? qkv[(64  + c) * PIX + src] : 0.f;
    VV[idx] = ok ? qkv[(128 + c) * PIX + src] : 0.f;
}

// ---------------- K3: attention (flash-style, no-max softmax) ----------------
// grid: 4 heads * 128 qtiles(32 queries) = 512 blocks, 256 threads
__global__ __launch_bounds__(256)
void k_attn(const float* __restrict__ qkv, const float* __restrict__ KK,
            const float* __restrict__ VV, float* __restrict__ AO)
{
    __shared__ float smem[8736];   // kt[4096] | vt[4096]  (reused: part[8192], dens[512], dinv[32])
    float* kt = smem;
    float* vt = smem + 4096;

    const int tid  = threadIdx.x;
    const int head = blockIdx.x >> 7;
    const int qt   = blockIdx.x & 127;
    const int pbase = qt * 32;
    const int qp = tid & 15;     // query pair -> q0 = 2*qp
    const int ml = tid >> 4;     // 0..15 m-lane
    const int q0 = 2 * qp;

    float qr0[16], qr1[16], acc0[16], acc1[16];
    #pragma unroll
    for (int dd = 0; dd < 16; ++dd) {
        qr0[dd] = qkv[(head * 16 + dd) * PIX + pbase + q0]     * 0.25f;
        qr1[dd] = qkv[(head * 16 + dd) * PIX + pbase + q0 + 1] * 0.25f;
        acc0[dd] = 0.f; acc1[dd] = 0.f;
    }
    float den0 = 0.f, den1 = 0.f;

    const float* Kh = KK + head * MKEYS;
    const float* Vh = VV + head * MKEYS;

    for (int t = 0; t < 36; ++t) {
        const int base = t * 4096;
        #pragma unroll
        for (int j = 0; j < 4; ++j) {
            int off = (j * 256 + tid) * 4;
            *(float4*)&kt[off] = *(const float4*)&Kh[base + off];
            *(float4*)&vt[off] = *(const float4*)&Vh[base + off];
        }
        __syncthreads();

        #pragma unroll
        for (int i = 0; i < 16; ++i) {
            const int m_l = i * 16 + ml;     // ml contiguous in wave -> 2-way (free) LDS conflicts
            const float4 k0 = *(const float4*)&kt[m_l * 16 + 0];
            const float4 k1 = *(const float4*)&kt[m_l * 16 + 4];
            const float4 k2 = *(const float4*)&kt[m_l * 16 + 8];
            const float4 k3 = *(const float4*)&kt[m_l * 16 + 12];

            float s00 = fmaf(qr0[0], k0.x, fmaf(qr0[1], k0.y, fmaf(qr0[2], k0.z, qr0[3] * k0.w)));
            float s01 = fmaf(qr0[4], k1.x, fmaf(qr0[5], k1.y, fmaf(qr0[6], k1.z, qr0[7] * k1.w)));
            float s02 = fmaf(qr0[8], k2.x, fmaf(qr0[9], k2.y, fmaf(qr0[10], k2.z, qr0[11] * k2.w)));
            float s03 = fmaf(qr0[12], k3.x, fmaf(qr0[13], k3.y, fmaf(qr0[14], k3.z, qr0[15] * k3.w)));
            float s10 = fmaf(qr1[0], k0.x, fmaf(qr1[1], k0.y, fmaf(qr1[2], k0.z, qr1[3] * k0.w)));
            float s11 = fmaf(qr1[4], k1.x, fmaf(qr1[5], k1.y, fmaf(qr1[6], k1.z, qr1[7] * k1.w)));
            float s12 = fmaf(qr1[8], k2.x, fmaf(qr1[9], k2.y, fmaf(qr1[10], k2.z, qr1[11] * k2.w)));
            float s13 = fmaf(qr1[12], k3.x, fmaf(qr1[13], k3.y, fmaf(qr1[14], k3.z, qr1[15] * k3.w)));
            float d0 = (s00 + s01) + (s02 + s03);
            float d1 = (s10 + s11) + (s12 + s13);
            float p0 = __expf(d0);
            float p1 = __expf(d1);
            den0 += p0; den1 += p1;

            const float4 v0 = *(const float4*)&vt[m_l * 16 + 0];
            const float4 v1 = *(const float4*)&vt[m_l * 16 + 4];
            const float4 v2 = *(const float4*)&vt[m_l * 16 + 8];
            const float4 v3 = *(const float4*)&vt[m_l * 16 + 12];
            acc0[0]  = fmaf(p0, v0.x, acc0[0]);  acc0[1]  = fmaf(p0, v0.y, acc0[1]);
            acc0[2]  = fmaf(p0, v0.z, acc0[2]);  acc0[3]  = fmaf(p0, v0.w, acc0[3]);
            acc0[4]  = fmaf(p0, v1.x, acc0[4]);  acc0[5]  = fmaf(p0, v1.y, acc0[5]);
            acc0[6]  = fmaf(p0, v1.z, acc0[6]);  acc0[7]  = fmaf(p0, v1.w, acc0[7]);
            acc0[8]  = fmaf(p0, v2.x, acc0[8]);  acc0[9]  = fmaf(p0, v2.y, acc0[9]);
            acc0[10] = fmaf(p0, v2.z, acc0[10]); acc0[11] = fmaf(p0, v2.w, acc0[11]);
            acc0[12] = fmaf(p0, v3.x, acc0[12]); acc0[13] = fmaf(p0, v3.y, acc0[13]);
            acc0[14] = fmaf(p0, v3.z, acc0[14]); acc0[15] = fmaf(p0, v3.w, acc0[15]);
            acc1[0]  = fmaf(p1, v0.x, acc1[0]);  acc1[1]  = fmaf(p1, v0.y, acc1[1]);
            acc1[2]  = fmaf(p1, v0.z, acc1[2]);  acc1[3]  = fmaf(p1, v0.w, acc1[3]);
            acc1[4]  = fmaf(p1, v1.x, acc1[4]);  acc1[5]  = fmaf(p1, v1.y, acc1[5]);
            acc1[6]  = fmaf(p1, v1.z, acc1[6]);  acc1[7]  = fmaf(p1, v1.w, acc1[7]);
            acc1[8]  = fmaf(p1, v2.x, acc1[8]);  acc1[9]  = fmaf(p1, v2.y, acc1[9]);
            acc1[10] = fmaf(p1, v2.z, acc1[10]); acc1[11] = fmaf(p1, v2.w, acc1[11]);
            acc1[12] = fmaf(p1, v3.x, acc1[12]); acc1[13] = fmaf(p1, v3.y, acc1[13]);
            acc1[14] = fmaf(p1, v3.z, acc1[14]); acc1[15] = fmaf(p1, v3.w, acc1[15]);
        }
        __syncthreads();
    }

    // cross-mlane reduction via LDS (reuse smem)
    float* part = smem;          // [16][32][16]
    float* dens = smem + 8192;   // [16][32]
    float* dinv = smem + 8704;   // [32]
    #pragma unroll
    for (int dd = 0; dd < 16; ++dd) {
        part[(ml * 32 + q0) * 16 + dd]     = acc0[dd];
        part[(ml * 32 + q0 + 1) * 16 + dd] = acc1[dd];
    }
    dens[ml * 32 + q0]     = den0;
    dens[ml * 32 + q0 + 1] = den1;
    __syncthreads();
    if (tid < 32) {
        float s = 0.f;
        #pragma unroll
        for (int j = 0; j < 16; ++j) s += dens[j * 32 + tid];
        dinv[tid] = 1.0f / s;
    }
    __syncthreads();
    #pragma unroll
    for (int rr = 0; rr < 2; ++rr) {
        int slot = tid + 256 * rr;      // 0..511
        int q = slot >> 4, dd = slot & 15;
        float s = 0.f;
        #pragma unroll
        for (int j = 0; j < 16; ++j) s += part[(j * 32 + q) * 16 + dd];
        AO[(head * 16 + dd) * PIX + pbase + q] = s * dinv[q];
    }
}

// ---------------- K4: output projection ----------------
// grid 64 (64 pixels each), block 256
__global__ __launch_bounds__(256)
void k_proj(const float* __restrict__ AO, const float* __restrict__ w_out,
            float* __restrict__ out)
{
    __shared__ float as_[64 * 64];   // as_[i][pl]
    __shared__ float wo[64 * 64];    // wo[o][i]
    const int tid = threadIdx.x;
    const int pbase = blockIdx.x * 64;
    for (int idx = tid; idx < 4096; idx += 256) {
        int i = idx >> 6, pl = idx & 63;
        as_[idx] = AO[i * PIX + pbase + pl];
        wo[idx]  = w_out[idx];
    }
    __syncthreads();
    const int pl = tid & 63;
    const int og = tid >> 6;   // o = og*16 + j
    float accs[16];
    #pragma unroll
    for (int j = 0; j < 16; ++j) accs[j] = 0.f;
    for (int c4 = 0; c4 < 64; c4 += 4) {
        float x0 = as_[(c4 + 0) * 64 + pl];
        float x1 = as_[(c4 + 1) * 64 + pl];
        float x2 = as_[(c4 + 2) * 64 + pl];
        float x3 = as_[(c4 + 3) * 64 + pl];
        #pragma unroll
        for (int j = 0; j < 16; ++j) {
            const float4 w4 = *(const float4*)&wo[(og * 16 + j) * 64 + c4];
            accs[j] = fmaf(x0, w4.x, fmaf(x1, w4.y, fmaf(x2, w4.z, fmaf(x3, w4.w, accs[j]))));
        }
    }
    #pragma unroll
    for (int j = 0; j < 16; ++j)
        out[(og * 16 + j) * PIX + pbase + pl] = accs[j];
}

extern "C" void kernel_launch(void* const* d_in, const int* in_sizes, int n_in,
                              void* d_out, int out_size, void* d_ws, size_t ws_size,
                              hipStream_t stream)
{
    const float* x     = (const float*)d_in[0];
    const float* w_qkv = (const float*)d_in[1];
    const float* w_out = (const float*)d_in[2];
    const float* ln_w  = (const float*)d_in[3];
    float* out = (float*)d_out;
    float* ws  = (float*)d_ws;

    float* qkv = ws + OFF_QKV;
    float* KK  = ws + OFF_KK;
    float* VV  = ws + OFF_VV;
    float* AO  = ws + OFF_AO;

    k_norm_qkv<<<dim3(128), dim3(256), 0, stream>>>(x, w_qkv, ln_w, qkv);
    k_unfold<<<dim3(2304), dim3(256), 0, stream>>>(qkv, KK, VV);
    k_attn<<<dim3(512), dim3(256), 0, stream>>>(qkv, KK, VV, AO);
    k_proj<<<dim3(64), dim3(256), 0, stream>>>(AO, w_out, out);
}

// Round 3
// 163.312 us; speedup vs baseline: 1.6191x; 1.6191x over previous
//
#include <hip/hip_runtime.h>
#include <math.h>

#define PIX 4096
typedef unsigned short ushort_t;
typedef unsigned int uint_t;
typedef __attribute__((ext_vector_type(8))) short bf16x8;
typedef __attribute__((ext_vector_type(16))) float f32x16;

// ---- ws layout ----
// float region:
//   qkv  [192][4096]   at float offset 0        (786432 floats)
//   AO   [4096][64]    at float offset 786432   (262144 floats)  layout [pix][h*16+d]
// ushort region at float offset 1048576 (byte offset 4 MiB):
#define U_QH 0               // [4][4096][16]
#define U_QL 262144
#define U_KH 524288          // [4][9216][16]
#define U_KL 1114112
#define U_VT 1703936         // [4][32][9216]  rows 0..15 = v_hi(d), 16..31 = v_lo(d)
#define OFF_AO 786432
#define OFF_USHORT 1048576

__device__ __forceinline__ void split_trunc(float x, ushort_t& hb, ushort_t& lb) {
    uint_t u = __float_as_uint(x);
    uint_t t = u & 0xFFFF0000u;
    float lo = x - __uint_as_float(t);
    hb = (ushort_t)(u >> 16);
    lb = (ushort_t)(__float_as_uint(lo) >> 16);
}

// ---------------- K1: norm + qkv projection (unchanged, verified) ----------------
__global__ __launch_bounds__(256)
void k_norm_qkv(const float* __restrict__ x, const float* __restrict__ w_qkv,
                const float* __restrict__ ln_w, float* __restrict__ qkv)
{
    __shared__ float xs[64 * 32];
    __shared__ float ws[192 * 64];
    __shared__ float rs[32];
    const int tid = threadIdx.x;
    const int pbase = blockIdx.x * 32;

    for (int idx = tid; idx < 2048; idx += 256) {
        int c = idx >> 5, pl = idx & 31;
        xs[idx] = x[c * PIX + pbase + pl];
    }
    for (int idx = tid; idx < 192 * 64; idx += 256) ws[idx] = w_qkv[idx];
    __syncthreads();

    if (tid < 32) {
        float s = 0.f, s2 = 0.f;
        #pragma unroll
        for (int c = 0; c < 64; ++c) {
            float v = xs[c * 32 + tid];
            s += v; s2 = fmaf(v, v, s2);
        }
        float mean = s * 0.015625f;
        float var  = fmaf(-mean, mean, s2 * 0.015625f);
        rs[tid] = 1.0f / sqrtf(var + 1e-5f);
    }
    __syncthreads();
    for (int idx = tid; idx < 2048; idx += 256) {
        int c = idx >> 5, pl = idx & 31;
        xs[idx] *= rs[pl] * ln_w[c];
    }
    __syncthreads();

    const int pl = tid & 31;
    const int og = tid >> 5;
    float accs[24];
    #pragma unroll
    for (int j = 0; j < 24; ++j) accs[j] = 0.f;

    for (int c4 = 0; c4 < 64; c4 += 4) {
        float xv0 = xs[(c4 + 0) * 32 + pl];
        float xv1 = xs[(c4 + 1) * 32 + pl];
        float xv2 = xs[(c4 + 2) * 32 + pl];
        float xv3 = xs[(c4 + 3) * 32 + pl];
        #pragma unroll
        for (int j = 0; j < 24; ++j) {
            const float4 w4 = *(const float4*)&ws[(og * 24 + j) * 64 + c4];
            accs[j] = fmaf(xv0, w4.x, fmaf(xv1, w4.y, fmaf(xv2, w4.z, fmaf(xv3, w4.w, accs[j]))));
        }
    }
    #pragma unroll
    for (int j = 0; j < 24; ++j)
        qkv[(og * 24 + j) * PIX + pbase + pl] = accs[j];
}

// ---------------- K2a: Q prep (scale 0.25, bf16 hi/lo split) ----------------
__global__ __launch_bounds__(256)
void k_prep_q(const float* __restrict__ qkv, ushort_t* __restrict__ QH, ushort_t* __restrict__ QL)
{
    int idx = blockIdx.x * 256 + threadIdx.x;   // < 262144
    int d = idx & 15, pix = (idx >> 4) & 4095, h = idx >> 16;
    float q = qkv[(h * 16 + d) * PIX + pix] * 0.25f;
    ushort_t hb, lb; split_trunc(q, hb, lb);
    QH[idx] = hb; QL[idx] = lb;
}

// ---------------- K2b: K unfold-gather + split -> KH, KL [4][9216][16] ----------------
__global__ __launch_bounds__(256)
void k_prep_k(const float* __restrict__ qkv, ushort_t* __restrict__ KH, ushort_t* __restrict__ KL)
{
    int idx = blockIdx.x * 256 + threadIdx.x;   // < 589824
    int h = idx / 147456;
    int r = idx - h * 147456;
    int m = r >> 4;
    int d = r & 15;
    int cc  = m / 576;
    int r2  = m - cc * 576;
    int orr = r2 / 48;
    int r3  = r2 - orr * 48;
    int oc  = r3 >> 2;
    int wg  = r3 & 3;
    int row = wg * 16 + (d >> 3) * 8 + orr - 2;
    int col = (d & 7) * 8 + oc - 2;
    int c   = h * 16 + cc;
    bool ok = ((unsigned)row < 64u) && ((unsigned)col < 64u);
    float v = ok ? qkv[(64 + c) * PIX + row * 64 + col] : 0.f;
    ushort_t hb, lb; split_trunc(v, hb, lb);
    KH[idx] = hb; KL[idx] = lb;
}

// ---------------- K2c: V unfold-gather + split -> VT [4][32][9216] (d-major) ----------------
__global__ __launch_bounds__(256)
void k_prep_vt(const float* __restrict__ qkv, ushort_t* __restrict__ VT)
{
    int idx = blockIdx.x * 256 + threadIdx.x;   // < 589824
    int h = idx / 147456;
    int r = idx - h * 147456;
    int d = r / 9216;
    int m = r - d * 9216;
    int cc  = m / 576;
    int r2  = m - cc * 576;
    int orr = r2 / 48;
    int r3  = r2 - orr * 48;
    int oc  = r3 >> 2;
    int wg  = r3 & 3;
    int row = wg * 16 + (d >> 3) * 8 + orr - 2;
    int col = (d & 7) * 8 + oc - 2;
    int c   = h * 16 + cc;
    bool ok = ((unsigned)row < 64u) && ((unsigned)col < 64u);
    float v = ok ? qkv[(128 + c) * PIX + row * 64 + col] : 0.f;
    ushort_t hb, lb; split_trunc(v, hb, lb);
    VT[(h * 32 + d) * 9216 + m]        = hb;
    VT[(h * 32 + 16 + d) * 9216 + m]   = lb;
}

// ---------------- K3: MFMA attention ----------------
// grid 512 blocks x 512 threads. block -> (head, 32-query tile) with XCD-aware map.
// Each of 8 waves handles 1152 keys (36 chunks of 32), LDS-combines at the end.
__global__ __launch_bounds__(512, 4)
void k_attn(const ushort_t* __restrict__ QH, const ushort_t* __restrict__ QL,
            const ushort_t* __restrict__ KH, const ushort_t* __restrict__ KL,
            const ushort_t* __restrict__ VT, float* __restrict__ AO)
{
    __shared__ float racc[8][64][16];   // 32 KB
    __shared__ float rden[8][64];       // 2 KB

    const int tid = threadIdx.x;
    const int w   = tid >> 6;
    const int l   = tid & 63;
    const int col = l & 31;     // QK: q-col & K-row; PV: q-row & dsplit-col
    const int rl  = l >> 5;

    const int bid  = blockIdx.x;
    const int x    = bid & 7;            // XCD slot (assumed bid%8 round-robin)
    const int g    = bid >> 3;
    const int h    = x >> 1;             // 2 XCDs per head -> head K/V fits 4MB L2
    const int tile = (g << 1) | (x & 1); // 0..127
    const int qbase = tile * 32;

    const bf16x8 qh = *(const bf16x8*)&QH[((h << 12) + qbase + col) * 16 + rl * 8];
    const bf16x8 ql = *(const bf16x8*)&QL[((h << 12) + qbase + col) * 16 + rl * 8];

    f32x16 acc = {0,0,0,0,0,0,0,0,0,0,0,0,0,0,0,0};
    const f32x16 zero = {0,0,0,0,0,0,0,0,0,0,0,0,0,0,0,0};
    float den = 0.f;

    const ushort_t* KHh = KH + h * 147456;
    const ushort_t* KLh = KL + h * 147456;
    const ushort_t* VTh = VT + h * (32 * 9216);

    for (int i = 0; i < 36; ++i) {
        const int mbase = (w * 36 + i) * 32;
        const bf16x8 kh = *(const bf16x8*)&KHh[(mbase + col) * 16 + rl * 8];
        const bf16x8 kl = *(const bf16x8*)&KLh[(mbase + col) * 16 + rl * 8];

        // S[m][q], exact product via 3 MFMAs (lo*lo dropped, ~2^-18)
        f32x16 S = __builtin_amdgcn_mfma_f32_32x32x16_bf16(kh, qh, zero, 0, 0, 0);
        S = __builtin_amdgcn_mfma_f32_32x32x16_bf16(kl, qh, S, 0, 0, 0);
        S = __builtin_amdgcn_mfma_f32_32x32x16_bf16(kh, ql, S, 0, 0, 0);

        float p[16];
        #pragma unroll
        for (int r = 0; r < 16; ++r) { p[r] = __expf(S[r]); den += p[r]; }

        // Two K=16 PV chunks per 32-m tile. A-frag positions (lane-group g0=rl, slot j):
        // m' = {4*rl+0..3, 8+4*rl+0..3} (+16 for half 1) -- matches p-register rows directly,
        // V is loaded in the SAME m-order, so no cross-lane data movement is needed.
        #pragma unroll
        for (int half = 0; half < 2; ++half) {
            union { int i4[4]; bf16x8 v; } Ah, Al;
            #pragma unroll
            for (int j = 0; j < 4; ++j) {
                float x0 = p[half * 8 + 2 * j];
                float x1 = p[half * 8 + 2 * j + 1];
                uint_t u0 = __float_as_uint(x0), u1 = __float_as_uint(x1);
                uint_t t0 = u0 & 0xFFFF0000u,   t1 = u1 & 0xFFFF0000u;
                Ah.i4[j] = (int)(t1 | (u0 >> 16));
                float l0 = x0 - __uint_as_float(t0);
                float l1 = x1 - __uint_as_float(t1);
                Al.i4[j] = (int)((__float_as_uint(l1) & 0xFFFF0000u) | (__float_as_uint(l0) >> 16));
            }
            union { uint_t u4[4]; bf16x8 v; } Vb;
            const int mm = mbase + half * 16 + rl * 4;
            *(uint2*)&Vb.u4[0] = *(const uint2*)&VTh[col * 9216 + mm];
            *(uint2*)&Vb.u4[2] = *(const uint2*)&VTh[col * 9216 + mm + 8];
            acc = __builtin_amdgcn_mfma_f32_32x32x16_bf16(Ah.v, Vb.v, acc, 0, 0, 0);
            acc = __builtin_amdgcn_mfma_f32_32x32x16_bf16(Al.v, Vb.v, acc, 0, 0, 0);
        }
    }

    #pragma unroll
    for (int j = 0; j < 16; ++j) racc[w][l][j] = acc[j];
    rden[w][l] = den;
    __syncthreads();

    // final combine: thread -> (q, d); D rows: row = (reg&3) + 8*(reg>>2) + 4*(lane>>5)
    const int q = tid >> 4, d = tid & 15;
    const int rl2 = (q >> 2) & 1;
    const int jj  = (q >> 3) * 4 + (q & 3);
    float sum = 0.f, dn = 0.f;
    #pragma unroll
    for (int ww = 0; ww < 8; ++ww) {
        sum += racc[ww][rl2 * 32 + d][jj] + racc[ww][rl2 * 32 + 16 + d][jj];
        dn  += rden[ww][q] + rden[ww][q + 32];
    }
    AO[(qbase + q) * 64 + h * 16 + d] = sum / dn;
}

// ---------------- K4: output projection (AO is [pix][64]) ----------------
__global__ __launch_bounds__(256)
void k_proj(const float* __restrict__ AO, const float* __restrict__ w_out,
            float* __restrict__ out)
{
    __shared__ float as2[16 * 68];
    __shared__ float wo[64 * 68];
    const int tid = threadIdx.x;
    const int pbase = blockIdx.x * 16;
    for (int idx = tid; idx < 1024; idx += 256) {
        int pl = idx >> 6, i = idx & 63;
        as2[pl * 68 + i] = AO[(pbase + pl) * 64 + i];
    }
    for (int idx = tid; idx < 4096; idx += 256) {
        int o = idx >> 6, c = idx & 63;
        wo[o * 68 + c] = w_out[idx];
    }
    __syncthreads();
    const int pl = tid & 15;
    const int og = tid >> 4;    // 16 groups x 4 outputs
    float a0 = 0.f, a1 = 0.f, a2 = 0.f, a3 = 0.f;
    for (int c = 0; c < 64; c += 4) {
        const float4 xv = *(const float4*)&as2[pl * 68 + c];
        const float4 w0 = *(const float4*)&wo[(og * 4 + 0) * 68 + c];
        const float4 w1 = *(const float4*)&wo[(og * 4 + 1) * 68 + c];
        const float4 w2 = *(const float4*)&wo[(og * 4 + 2) * 68 + c];
        const float4 w3 = *(const float4*)&wo[(og * 4 + 3) * 68 + c];
        a0 = fmaf(xv.x, w0.x, fmaf(xv.y, w0.y, fmaf(xv.z, w0.z, fmaf(xv.w, w0.w, a0))));
        a1 = fmaf(xv.x, w1.x, fmaf(xv.y, w1.y, fmaf(xv.z, w1.z, fmaf(xv.w, w1.w, a1))));
        a2 = fmaf(xv.x, w2.x, fmaf(xv.y, w2.y, fmaf(xv.z, w2.z, fmaf(xv.w, w2.w, a2))));
        a3 = fmaf(xv.x, w3.x, fmaf(xv.y, w3.y, fmaf(xv.z, w3.z, fmaf(xv.w, w3.w, a3))));
    }
    out[(og * 4 + 0) * PIX + pbase + pl] = a0;
    out[(og * 4 + 1) * PIX + pbase + pl] = a1;
    out[(og * 4 + 2) * PIX + pbase + pl] = a2;
    out[(og * 4 + 3) * PIX + pbase + pl] = a3;
}

extern "C" void kernel_launch(void* const* d_in, const int* in_sizes, int n_in,
                              void* d_out, int out_size, void* d_ws, size_t ws_size,
                              hipStream_t stream)
{
    const float* x     = (const float*)d_in[0];
    const float* w_qkv = (const float*)d_in[1];
    const float* w_out = (const float*)d_in[2];
    const float* ln_w  = (const float*)d_in[3];
    float* out = (float*)d_out;
    float* ws  = (float*)d_ws;

    float*    qkv = ws;
    float*    AO  = ws + OFF_AO;
    ushort_t* U   = (ushort_t*)(ws + OFF_USHORT);
    ushort_t* QH  = U + U_QH;
    ushort_t* QL  = U + U_QL;
    ushort_t* KH  = U + U_KH;
    ushort_t* KL  = U + U_KL;
    ushort_t* VT  = U + U_VT;

    k_norm_qkv<<<dim3(128),  dim3(256), 0, stream>>>(x, w_qkv, ln_w, qkv);
    k_prep_q  <<<dim3(1024), dim3(256), 0, stream>>>(qkv, QH, QL);
    k_prep_k  <<<dim3(2304), dim3(256), 0, stream>>>(qkv, KH, KL);
    k_prep_vt <<<dim3(2304), dim3(256), 0, stream>>>(qkv, VT);
    k_attn    <<<dim3(512),  dim3(512), 0, stream>>>(QH, QL, KH, KL, VT, AO);
    k_proj    <<<dim3(256),  dim3(256), 0, stream>>>(AO, w_out, out);
}

// Round 4
// 157.589 us; speedup vs baseline: 1.6779x; 1.0363x over previous
//
#include <hip/hip_runtime.h>
#include <math.h>

#define PIX 4096
typedef unsigned short ushort_t;
typedef unsigned int uint_t;
typedef __attribute__((ext_vector_type(8))) short bf16x8;
typedef __attribute__((ext_vector_type(16))) float f32x16;

// ---- ws layout ----
// float region:
//   qkvB [128][4096]  @ 0        (k channels 0..63, v channels 64..127)
//   AO0  [4096][64]   @ 524288   (raw PV sums, key-split 0)
//   AO1  [4096][64]   @ 786432   (key-split 1)
//   DN0  [4][4096]    @ 1048576  (softmax denominators, split 0)
//   DN1  [4][4096]    @ 1064960
// ushort region @ float offset 1081344:
//   QH [4][4096][16] @ 0         QL @ 262144
//   KF [4][288][1024] @ 524288   (per 32-key chunk: 512 hi + 512 lo, lane-frag order)
//   VF [4][288][1024] @ 1703936  (per chunk: 512 half0 + 512 half1, lane-frag order)
#define OFF_AO0 524288
#define OFF_AO1 786432
#define OFF_DN0 1048576
#define OFF_DN1 1064960
#define OFF_USHORT 1081344
#define U_QH 0
#define U_QL 262144
#define U_KF 524288
#define U_VF 1703936

// 0.25 (DH^-0.5) * log2(e): softmax uses exp2 directly
#define QSCALE 0.36067376022224087f

#if defined(__has_builtin)
#if __has_builtin(__builtin_amdgcn_exp2f)
#define EXP2F(x) __builtin_amdgcn_exp2f(x)
#endif
#if __has_builtin(__builtin_amdgcn_perm)
#define PKHI16(u1, u0) __builtin_amdgcn_perm((u1), (u0), 0x07060302u)
#endif
#endif
#ifndef EXP2F
#define EXP2F(x) exp2f(x)
#endif
#ifndef PKHI16
#define PKHI16(u1, u0) (((u0) >> 16) | ((u1) & 0xFFFF0000u))
#endif

__device__ __forceinline__ void split_trunc(float x, ushort_t& hb, ushort_t& lb) {
    uint_t u = __float_as_uint(x);
    uint_t t = u & 0xFFFF0000u;
    float lo = x - __uint_as_float(t);
    hb = (ushort_t)(u >> 16);
    lb = (ushort_t)(__float_as_uint(lo) >> 16);
}

// ---------------- K1: norm + qkv projection + fused Q hi/lo prep ----------------
// grid 256 (16 pixels each), block 256
__global__ __launch_bounds__(256)
void k_norm_qkv(const float* __restrict__ x, const float* __restrict__ w_qkv,
                const float* __restrict__ ln_w, float* __restrict__ qkvB,
                ushort_t* __restrict__ QH, ushort_t* __restrict__ QL)
{
    __shared__ float xs[64 * 16];
    __shared__ float ws[192 * 64];
    __shared__ float rs[16];
    const int tid = threadIdx.x;
    const int pbase = blockIdx.x * 16;

    for (int idx = tid; idx < 1024; idx += 256) {
        int c = idx >> 4, pl = idx & 15;
        xs[idx] = x[c * PIX + pbase + pl];
    }
    for (int idx = tid; idx < 192 * 64; idx += 256) ws[idx] = w_qkv[idx];
    __syncthreads();

    if (tid < 16) {
        float s = 0.f, s2 = 0.f;
        #pragma unroll
        for (int c = 0; c < 64; ++c) {
            float v = xs[c * 16 + tid];
            s += v; s2 = fmaf(v, v, s2);
        }
        float mean = s * 0.015625f;
        float var  = fmaf(-mean, mean, s2 * 0.015625f);
        rs[tid] = 1.0f / sqrtf(var + 1e-5f);
    }
    __syncthreads();
    for (int idx = tid; idx < 1024; idx += 256) {
        int c = idx >> 4, pl = idx & 15;
        xs[idx] *= rs[pl] * ln_w[c];
    }
    __syncthreads();

    const int pl = tid & 15;
    const int og = tid >> 4;      // 16 groups x 12 outputs
    float accs[12];
    #pragma unroll
    for (int j = 0; j < 12; ++j) accs[j] = 0.f;

    for (int c4 = 0; c4 < 64; c4 += 4) {
        float xv0 = xs[(c4 + 0) * 16 + pl];
        float xv1 = xs[(c4 + 1) * 16 + pl];
        float xv2 = xs[(c4 + 2) * 16 + pl];
        float xv3 = xs[(c4 + 3) * 16 + pl];
        #pragma unroll
        for (int j = 0; j < 12; ++j) {
            const float4 w4 = *(const float4*)&ws[(og * 12 + j) * 64 + c4];
            accs[j] = fmaf(xv0, w4.x, fmaf(xv1, w4.y, fmaf(xv2, w4.z, fmaf(xv3, w4.w, accs[j]))));
        }
    }
    #pragma unroll
    for (int j = 0; j < 12; ++j) {
        const int o = og * 12 + j;
        if (o < 64) {
            float qv = accs[j] * QSCALE;
            ushort_t hb, lb; split_trunc(qv, hb, lb);
            const int h = o >> 4, d = o & 15;
            const int a = (h * PIX + pbase + pl) * 16 + d;
            QH[a] = hb; QL[a] = lb;
        } else {
            qkvB[(o - 64) * PIX + pbase + pl] = accs[j];
        }
    }
}

// ---------------- K2: fused K+V unfold-gather into lane-fragment layouts ----------------
// grid 4608 x 256: blocks [0,2304) = K elements, [2304,4608) = V elements
__global__ __launch_bounds__(256)
void k_prep_kv(const float* __restrict__ qkvB,
               ushort_t* __restrict__ KF, ushort_t* __restrict__ VF)
{
    const int t = blockIdx.x * 256 + threadIdx.x;
    if (t < 589824) {
        // K: thread per (h, chunk i, lane l, j)
        int h = t / 147456; int r = t - h * 147456;
        int i = r >> 9; int r2 = r & 511;
        int l = r2 >> 3, j = r2 & 7;
        int col = l & 31, rl = l >> 5;
        int m = i * 32 + col;
        int d = rl * 8 + j;
        int cc = m / 576;  int r3 = m - cc * 576;
        int orr = r3 / 48; int r4 = r3 - orr * 48;
        int oc = r4 >> 2, wg = r4 & 3;
        int row  = wg * 16 + (d >> 3) * 8 + orr - 2;
        int colp = (d & 7) * 8 + oc - 2;
        bool ok = ((unsigned)row < 64u) && ((unsigned)colp < 64u);
        float v = ok ? qkvB[(h * 16 + cc) * PIX + row * 64 + colp] : 0.f;
        ushort_t hb, lb; split_trunc(v, hb, lb);
        int base = (h * 288 + i) * 1024 + l * 8 + j;
        KF[base] = hb; KF[base + 512] = lb;
    } else {
        // V: thread per (h, chunk i, half, rl, colD, j2); writes hi lane colD, lo lane colD+16
        int t2 = t - 589824;
        int h = t2 / 147456; int r = t2 - h * 147456;
        int i = r >> 9; int r2 = r & 511;
        int half = r2 >> 8; int r3 = r2 & 255;
        int rl = r3 >> 7; int colD = (r3 >> 3) & 15; int j2 = r3 & 7;
        int m = i * 32 + half * 16 + rl * 4 + (j2 & 3) + 8 * (j2 >> 2);
        int d = colD;
        int cc = m / 576;  int r4 = m - cc * 576;
        int orr = r4 / 48; int r5 = r4 - orr * 48;
        int oc = r5 >> 2, wg = r5 & 3;
        int row  = wg * 16 + (d >> 3) * 8 + orr - 2;
        int colp = (d & 7) * 8 + oc - 2;
        bool ok = ((unsigned)row < 64u) && ((unsigned)colp < 64u);
        float v = ok ? qkvB[(64 + h * 16 + cc) * PIX + row * 64 + colp] : 0.f;
        ushort_t hb, lb; split_trunc(v, hb, lb);
        int cb = (h * 288 + i) * 1024 + half * 512;
        VF[cb + (rl * 32 + colD) * 8 + j2]      = hb;
        VF[cb + (rl * 32 + colD + 16) * 8 + j2] = lb;
    }
}

// ---------------- K3: MFMA attention, coalesced frag loads, 2-way key split ----------------
// grid 1024 x 512. bid -> (XCD x = bid&7 -> head = x>>1; tile; key-split ks)
__global__ __launch_bounds__(512, 8)
void k_attn(const ushort_t* __restrict__ QH, const ushort_t* __restrict__ QL,
            const ushort_t* __restrict__ KF, const ushort_t* __restrict__ VF,
            float* __restrict__ AO0, float* __restrict__ AO1,
            float* __restrict__ DN0, float* __restrict__ DN1)
{
    __shared__ float racc[8][64][16];
    __shared__ float rden[8][64];

    const int tid = threadIdx.x;
    const int w   = tid >> 6;
    const int l   = tid & 63;
    const int col = l & 31;
    const int rl  = l >> 5;

    const int bid  = blockIdx.x;
    const int x    = bid & 7;
    const int g    = bid >> 3;
    const int h    = x >> 1;
    const int tile = ((g & 63) << 1) | (x & 1);
    const int ks   = g >> 6;
    const int qbase = tile * 32;

    const bf16x8 qh = *(const bf16x8*)&QH[((h << 12) + qbase + col) * 16 + rl * 8];
    const bf16x8 ql = *(const bf16x8*)&QL[((h << 12) + qbase + col) * 16 + rl * 8];

    f32x16 acc = {0,0,0,0,0,0,0,0,0,0,0,0,0,0,0,0};
    const f32x16 zero = {0,0,0,0,0,0,0,0,0,0,0,0,0,0,0,0};
    float den = 0.f;

    for (int i = 0; i < 18; ++i) {
        const int ib = ks * 144 + w * 18 + i;
        const ushort_t* kb = KF + (h * 288 + ib) * 1024;
        const ushort_t* vb = VF + (h * 288 + ib) * 1024;
        const bf16x8 kh = *(const bf16x8*)&kb[l * 8];
        const bf16x8 kl = *(const bf16x8*)&kb[l * 8 + 512];

        f32x16 S = __builtin_amdgcn_mfma_f32_32x32x16_bf16(kh, qh, zero, 0, 0, 0);
        S = __builtin_amdgcn_mfma_f32_32x32x16_bf16(kl, qh, S, 0, 0, 0);
        S = __builtin_amdgcn_mfma_f32_32x32x16_bf16(kh, ql, S, 0, 0, 0);

        float p[16];
        #pragma unroll
        for (int r = 0; r < 16; ++r) { p[r] = EXP2F(S[r]); den += p[r]; }

        #pragma unroll
        for (int half = 0; half < 2; ++half) {
            union { uint_t i4[4]; bf16x8 v; } Ah, Al;
            #pragma unroll
            for (int j = 0; j < 4; ++j) {
                float x0 = p[half * 8 + 2 * j];
                float x1 = p[half * 8 + 2 * j + 1];
                uint_t u0 = __float_as_uint(x0), u1 = __float_as_uint(x1);
                Ah.i4[j] = PKHI16(u1, u0);
                float l0 = x0 - __uint_as_float(u0 & 0xFFFF0000u);
                float l1 = x1 - __uint_as_float(u1 & 0xFFFF0000u);
                Al.i4[j] = PKHI16(__float_as_uint(l1), __float_as_uint(l0));
            }
            const bf16x8 Vb = *(const bf16x8*)&vb[half * 512 + l * 8];
            acc = __builtin_amdgcn_mfma_f32_32x32x16_bf16(Ah.v, Vb, acc, 0, 0, 0);
            acc = __builtin_amdgcn_mfma_f32_32x32x16_bf16(Al.v, Vb, acc, 0, 0, 0);
        }
    }

    #pragma unroll
    for (int j = 0; j < 16; ++j) racc[w][l][j] = acc[j];
    rden[w][l] = den;
    __syncthreads();

    const int q = tid >> 4, d = tid & 15;
    const int rl2 = (q >> 2) & 1;
    const int jj  = (q >> 3) * 4 + (q & 3);
    float sum = 0.f, dn = 0.f;
    #pragma unroll
    for (int ww = 0; ww < 8; ++ww) {
        sum += racc[ww][rl2 * 32 + d][jj] + racc[ww][rl2 * 32 + 16 + d][jj];
        dn  += rden[ww][q] + rden[ww][q + 32];
    }
    float* AOp = ks ? AO1 : AO0;
    AOp[(qbase + q) * 64 + h * 16 + d] = sum;
    if (d == 0) (ks ? DN1 : DN0)[h * PIX + qbase + q] = dn;
}

// ---------------- K4: partial combine + output projection ----------------
// grid 256 (16 pixels each), block 256
__global__ __launch_bounds__(256)
void k_proj(const float* __restrict__ AO0, const float* __restrict__ AO1,
            const float* __restrict__ DN0, const float* __restrict__ DN1,
            const float* __restrict__ w_out, float* __restrict__ out)
{
    __shared__ float as2[16 * 68];
    __shared__ float wo[64 * 68];
    __shared__ float rdn[64];   // [h][pl]
    const int tid = threadIdx.x;
    const int pbase = blockIdx.x * 16;

    if (tid < 64) {
        int h = tid >> 4, pl = tid & 15;
        rdn[tid] = 1.0f / (DN0[h * PIX + pbase + pl] + DN1[h * PIX + pbase + pl]);
    }
    for (int idx = tid; idx < 4096; idx += 256) {
        int o = idx >> 6, c = idx & 63;
        wo[o * 68 + c] = w_out[idx];
    }
    __syncthreads();
    for (int idx = tid; idx < 1024; idx += 256) {
        int pl = idx >> 6, i = idx & 63;
        float s = AO0[(pbase + pl) * 64 + i] + AO1[(pbase + pl) * 64 + i];
        as2[pl * 68 + i] = s * rdn[(i >> 4) * 16 + pl];
    }
    __syncthreads();

    const int pl = tid & 15;
    const int og = tid >> 4;    // 16 groups x 4 outputs
    float a0 = 0.f, a1 = 0.f, a2 = 0.f, a3 = 0.f;
    for (int c = 0; c < 64; c += 4) {
        const float4 xv = *(const float4*)&as2[pl * 68 + c];
        const float4 w0 = *(const float4*)&wo[(og * 4 + 0) * 68 + c];
        const float4 w1 = *(const float4*)&wo[(og * 4 + 1) * 68 + c];
        const float4 w2 = *(const float4*)&wo[(og * 4 + 2) * 68 + c];
        const float4 w3 = *(const float4*)&wo[(og * 4 + 3) * 68 + c];
        a0 = fmaf(xv.x, w0.x, fmaf(xv.y, w0.y, fmaf(xv.z, w0.z, fmaf(xv.w, w0.w, a0))));
        a1 = fmaf(xv.x, w1.x, fmaf(xv.y, w1.y, fmaf(xv.z, w1.z, fmaf(xv.w, w1.w, a1))));
        a2 = fmaf(xv.x, w2.x, fmaf(xv.y, w2.y, fmaf(xv.z, w2.z, fmaf(xv.w, w2.w, a2))));
        a3 = fmaf(xv.x, w3.x, fmaf(xv.y, w3.y, fmaf(xv.z, w3.z, fmaf(xv.w, w3.w, a3))));
    }
    out[(og * 4 + 0) * PIX + pbase + pl] = a0;
    out[(og * 4 + 1) * PIX + pbase + pl] = a1;
    out[(og * 4 + 2) * PIX + pbase + pl] = a2;
    out[(og * 4 + 3) * PIX + pbase + pl] = a3;
}

extern "C" void kernel_launch(void* const* d_in, const int* in_sizes, int n_in,
                              void* d_out, int out_size, void* d_ws, size_t ws_size,
                              hipStream_t stream)
{
    const float* x     = (const float*)d_in[0];
    const float* w_qkv = (const float*)d_in[1];
    const float* w_out = (const float*)d_in[2];
    const float* ln_w  = (const float*)d_in[3];
    float* out = (float*)d_out;
    float* ws  = (float*)d_ws;

    float* qkvB = ws;
    float* AO0  = ws + OFF_AO0;
    float* AO1  = ws + OFF_AO1;
    float* DN0  = ws + OFF_DN0;
    float* DN1  = ws + OFF_DN1;
    ushort_t* U  = (ushort_t*)(ws + OFF_USHORT);
    ushort_t* QH = U + U_QH;
    ushort_t* QL = U + U_QL;
    ushort_t* KF = U + U_KF;
    ushort_t* VF = U + U_VF;

    k_norm_qkv<<<dim3(256),  dim3(256), 0, stream>>>(x, w_qkv, ln_w, qkvB, QH, QL);
    k_prep_kv <<<dim3(4608), dim3(256), 0, stream>>>(qkvB, KF, VF);
    k_attn    <<<dim3(1024), dim3(512), 0, stream>>>(QH, QL, KF, VF, AO0, AO1, DN0, DN1);
    k_proj    <<<dim3(256),  dim3(256), 0, stream>>>(AO0, AO1, DN0, DN1, w_out, out);
}

// Round 5
// 118.183 us; speedup vs baseline: 2.2373x; 1.3334x over previous
//
#include <hip/hip_runtime.h>
#include <math.h>

#define PIX 4096
typedef unsigned short ushort_t;
typedef unsigned int uint_t;
typedef __attribute__((ext_vector_type(8))) short bf16x8;
typedef __attribute__((ext_vector_type(16))) float f32x16;

// ---- ws layout ----
// float region:
//   qkvB [128][4096]  @ 0        (k channels 0..63, v channels 64..127)
//   AO0  [4096][64]   @ 524288   <- XH [4096][64] ushort aliases here pre-attn
//   AO1  [4096][64]   @ 786432   <- XL aliases here pre-attn
//   DN0  [4][4096]    @ 1048576
//   DN1  [4][4096]    @ 1064960
// ushort region @ float offset 1081344:
//   QH [4][4096][16] @ 0         QL @ 262144
//   KF [4][288][1024] @ 524288   VF [4][288][1024] @ 1703936
#define OFF_AO0 524288
#define OFF_AO1 786432
#define OFF_DN0 1048576
#define OFF_DN1 1064960
#define OFF_USHORT 1081344
#define U_QH 0
#define U_QL 262144
#define U_KF 524288
#define U_VF 1703936

// 0.25 (DH^-0.5) * log2(e): softmax uses exp2 directly
#define QSCALE 0.36067376022224087f

#if defined(__has_builtin)
#if __has_builtin(__builtin_amdgcn_exp2f)
#define EXP2F(x) __builtin_amdgcn_exp2f(x)
#endif
#if __has_builtin(__builtin_amdgcn_perm)
#define PKHI16(u1, u0) __builtin_amdgcn_perm((u1), (u0), 0x07060302u)
#endif
#endif
#ifndef EXP2F
#define EXP2F(x) exp2f(x)
#endif
#ifndef PKHI16
#define PKHI16(u1, u0) (((u0) >> 16) | ((u1) & 0xFFFF0000u))
#endif

__device__ __forceinline__ void split_trunc(float x, ushort_t& hb, ushort_t& lb) {
    uint_t u = __float_as_uint(x);
    uint_t t = u & 0xFFFF0000u;
    float lo = x - __uint_as_float(t);
    hb = (ushort_t)(u >> 16);
    lb = (ushort_t)(__float_as_uint(lo) >> 16);
}

__device__ __forceinline__ void split8(const float* v, bf16x8& H, bf16x8& L) {
    union { uint_t u[4]; bf16x8 b; } hh, ll;
    #pragma unroll
    for (int j = 0; j < 4; ++j) {
        uint_t u0 = __float_as_uint(v[2 * j]), u1 = __float_as_uint(v[2 * j + 1]);
        hh.u[j] = PKHI16(u1, u0);
        float l0 = v[2 * j]     - __uint_as_float(u0 & 0xFFFF0000u);
        float l1 = v[2 * j + 1] - __uint_as_float(u1 & 0xFFFF0000u);
        ll.u[j] = PKHI16(__float_as_uint(l1), __float_as_uint(l0));
    }
    H = hh.b; L = ll.b;
}

// ---------------- K1a: norm -> XH/XL [px][c] bf16 hi/lo ----------------
// grid 64 (64 px each), block 256
__global__ __launch_bounds__(256)
void k_norm(const float* __restrict__ x, const float* __restrict__ ln_w,
            ushort_t* __restrict__ XH, ushort_t* __restrict__ XL)
{
    __shared__ float xs[64 * 64];     // [c][px]
    __shared__ float red[2][4][64];
    __shared__ float rstd[64];
    __shared__ float lw[64];
    const int tid = threadIdx.x;
    const int px = tid & 63, cg = tid >> 6;
    const int pbase = blockIdx.x * 64;

    if (tid < 64) lw[tid] = ln_w[tid];
    float s = 0.f, s2 = 0.f;
    #pragma unroll
    for (int cl = 0; cl < 16; ++cl) {
        int c = cg * 16 + cl;
        float v = x[c * PIX + pbase + px];
        xs[c * 64 + px] = v;
        s += v; s2 = fmaf(v, v, s2);
    }
    red[0][cg][px] = s; red[1][cg][px] = s2;
    __syncthreads();
    if (tid < 64) {
        float a = red[0][0][tid] + red[0][1][tid] + red[0][2][tid] + red[0][3][tid];
        float b = red[1][0][tid] + red[1][1][tid] + red[1][2][tid] + red[1][3][tid];
        float mean = a * 0.015625f;
        float var  = fmaf(-mean, mean, b * 0.015625f);
        rstd[tid] = 1.0f / sqrtf(var + 1e-5f);
    }
    __syncthreads();
    const float r = rstd[px];
    float vals[16];
    #pragma unroll
    for (int cl = 0; cl < 16; ++cl) {
        int c = cg * 16 + cl;
        vals[cl] = xs[c * 64 + px] * r * lw[c];
    }
    bf16x8 H0, L0, H1, L1;
    split8(&vals[0], H0, L0);
    split8(&vals[8], H1, L1);
    const int base = (pbase + px) * 64 + cg * 16;
    *(bf16x8*)&XH[base]     = H0;
    *(bf16x8*)&XH[base + 8] = H1;
    *(bf16x8*)&XL[base]     = L0;
    *(bf16x8*)&XL[base + 8] = L1;
}

// ---------------- K1b: qkv projection GEMM (MFMA, hi/lo) ----------------
// grid 192, block 256 (4 waves). wave tile 32o x 32px.
__global__ __launch_bounds__(256)
void k_qkv(const float* __restrict__ w_qkv, const ushort_t* __restrict__ XH,
           const ushort_t* __restrict__ XL, float* __restrict__ qkvB,
           ushort_t* __restrict__ QH, ushort_t* __restrict__ QL)
{
    const int tid = threadIdx.x;
    const int w = tid >> 6, l = tid & 63;
    const int col = l & 31, rl = l >> 5;
    const int obase  = ((blockIdx.x >> 6) * 2 + (w >> 1)) * 32;
    const int pxbase = ((int)(blockIdx.x & 63) * 2 + (w & 1)) * 32;

    bf16x8 wh[4], wl[4], xh[4], xl[4];
    const float* wrow = w_qkv + (obase + col) * 64;
    #pragma unroll
    for (int s = 0; s < 4; ++s) {
        float tmp[8];
        *(float4*)&tmp[0] = *(const float4*)&wrow[s * 16 + rl * 8];
        *(float4*)&tmp[4] = *(const float4*)&wrow[s * 16 + rl * 8 + 4];
        split8(tmp, wh[s], wl[s]);
    }
    const ushort_t* xr  = XH + (pxbase + col) * 64;
    const ushort_t* xr2 = XL + (pxbase + col) * 64;
    #pragma unroll
    for (int s = 0; s < 4; ++s) {
        xh[s] = *(const bf16x8*)&xr[s * 16 + rl * 8];
        xl[s] = *(const bf16x8*)&xr2[s * 16 + rl * 8];
    }
    f32x16 acc = {0,0,0,0,0,0,0,0,0,0,0,0,0,0,0,0};
    #pragma unroll
    for (int s = 0; s < 4; ++s) {
        acc = __builtin_amdgcn_mfma_f32_32x32x16_bf16(wh[s], xh[s], acc, 0, 0, 0);
        acc = __builtin_amdgcn_mfma_f32_32x32x16_bf16(wl[s], xh[s], acc, 0, 0, 0);
        acc = __builtin_amdgcn_mfma_f32_32x32x16_bf16(wh[s], xl[s], acc, 0, 0, 0);
    }
    const int px = pxbase + col;
    if (obase < 64) {
        #pragma unroll
        for (int j = 0; j < 16; ++j) {
            int o = obase + (j & 3) + 8 * (j >> 2) + 4 * rl;
            float v = acc[j] * QSCALE;
            ushort_t hb, lb; split_trunc(v, hb, lb);
            int a = ((o >> 4) * PIX + px) * 16 + (o & 15);
            QH[a] = hb; QL[a] = lb;
        }
    } else {
        #pragma unroll
        for (int j = 0; j < 16; ++j) {
            int o = obase + (j & 3) + 8 * (j >> 2) + 4 * rl;
            qkvB[(o - 64) * PIX + px] = acc[j];
        }
    }
}

// ---------------- K2: fused K+V unfold-gather into lane-fragment layouts ----------------
__global__ __launch_bounds__(256)
void k_prep_kv(const float* __restrict__ qkvB,
               ushort_t* __restrict__ KF, ushort_t* __restrict__ VF)
{
    const int t = blockIdx.x * 256 + threadIdx.x;
    if (t < 589824) {
        int h = t / 147456; int r = t - h * 147456;
        int i = r >> 9; int r2 = r & 511;
        int l = r2 >> 3, j = r2 & 7;
        int col = l & 31, rl = l >> 5;
        int m = i * 32 + col;
        int d = rl * 8 + j;
        int cc = m / 576;  int r3 = m - cc * 576;
        int orr = r3 / 48; int r4 = r3 - orr * 48;
        int oc = r4 >> 2, wg = r4 & 3;
        int row  = wg * 16 + (d >> 3) * 8 + orr - 2;
        int colp = (d & 7) * 8 + oc - 2;
        bool ok = ((unsigned)row < 64u) && ((unsigned)colp < 64u);
        float v = ok ? qkvB[(h * 16 + cc) * PIX + row * 64 + colp] : 0.f;
        ushort_t hb, lb; split_trunc(v, hb, lb);
        int base = (h * 288 + i) * 1024 + l * 8 + j;
        KF[base] = hb; KF[base + 512] = lb;
    } else {
        int t2 = t - 589824;
        int h = t2 / 147456; int r = t2 - h * 147456;
        int i = r >> 9; int r2 = r & 511;
        int half = r2 >> 8; int r3 = r2 & 255;
        int rl = r3 >> 7; int colD = (r3 >> 3) & 15; int j2 = r3 & 7;
        int m = i * 32 + half * 16 + rl * 4 + (j2 & 3) + 8 * (j2 >> 2);
        int d = colD;
        int cc = m / 576;  int r4 = m - cc * 576;
        int orr = r4 / 48; int r5 = r4 - orr * 48;
        int oc = r5 >> 2, wg = r5 & 3;
        int row  = wg * 16 + (d >> 3) * 8 + orr - 2;
        int colp = (d & 7) * 8 + oc - 2;
        bool ok = ((unsigned)row < 64u) && ((unsigned)colp < 64u);
        float v = ok ? qkvB[(64 + h * 16 + cc) * PIX + row * 64 + colp] : 0.f;
        ushort_t hb, lb; split_trunc(v, hb, lb);
        int cb = (h * 288 + i) * 1024 + half * 512;
        VF[cb + (rl * 32 + colD) * 8 + j2]      = hb;
        VF[cb + (rl * 32 + colD + 16) * 8 + j2] = lb;
    }
}

// ---------------- K3: MFMA attention, prefetch-pipelined ----------------
__global__ __launch_bounds__(512, 4)
void k_attn(const ushort_t* __restrict__ QH, const ushort_t* __restrict__ QL,
            const ushort_t* __restrict__ KF, const ushort_t* __restrict__ VF,
            float* __restrict__ AO0, float* __restrict__ AO1,
            float* __restrict__ DN0, float* __restrict__ DN1)
{
    __shared__ float racc[8][64][16];
    __shared__ float rden[8][64];

    const int tid = threadIdx.x;
    const int w   = tid >> 6;
    const int l   = tid & 63;
    const int col = l & 31;
    const int rl  = l >> 5;

    const int bid  = blockIdx.x;
    const int x    = bid & 7;
    const int g    = bid >> 3;
    const int h    = x >> 1;
    const int tile = ((g & 63) << 1) | (x & 1);
    const int ks   = g >> 6;
    const int qbase = tile * 32;

    const bf16x8 qh = *(const bf16x8*)&QH[((h << 12) + qbase + col) * 16 + rl * 8];
    const bf16x8 ql = *(const bf16x8*)&QL[((h << 12) + qbase + col) * 16 + rl * 8];

    f32x16 acc = {0,0,0,0,0,0,0,0,0,0,0,0,0,0,0,0};
    const f32x16 zero = {0,0,0,0,0,0,0,0,0,0,0,0,0,0,0,0};
    float den = 0.f;

    const ushort_t* KFh = KF + h * (288 * 1024);
    const ushort_t* VFh = VF + h * (288 * 1024);
    const int ib0 = ks * 144 + w * 18;

    bf16x8 kh = *(const bf16x8*)&KFh[ib0 * 1024 + l * 8];
    bf16x8 kl = *(const bf16x8*)&KFh[ib0 * 1024 + 512 + l * 8];
    bf16x8 v0 = *(const bf16x8*)&VFh[ib0 * 1024 + l * 8];
    bf16x8 v1 = *(const bf16x8*)&VFh[ib0 * 1024 + 512 + l * 8];

    for (int i = 0; i < 18; ++i) {
        // compute with current regs; prefetch next chunk first so loads overlap
        bf16x8 ckh = kh, ckl = kl, cv0 = v0, cv1 = v1;
        if (i < 17) {
            const int a = (ib0 + i + 1) * 1024 + l * 8;
            kh = *(const bf16x8*)&KFh[a];
            kl = *(const bf16x8*)&KFh[a + 512];
            v0 = *(const bf16x8*)&VFh[a];
            v1 = *(const bf16x8*)&VFh[a + 512];
        }

        f32x16 S = __builtin_amdgcn_mfma_f32_32x32x16_bf16(ckh, qh, zero, 0, 0, 0);
        S = __builtin_amdgcn_mfma_f32_32x32x16_bf16(ckl, qh, S, 0, 0, 0);
        S = __builtin_amdgcn_mfma_f32_32x32x16_bf16(ckh, ql, S, 0, 0, 0);

        float p[16];
        #pragma unroll
        for (int r = 0; r < 16; ++r) { p[r] = EXP2F(S[r]); den += p[r]; }

        #pragma unroll
        for (int half = 0; half < 2; ++half) {
            union { uint_t i4[4]; bf16x8 v; } Ah, Al;
            #pragma unroll
            for (int j = 0; j < 4; ++j) {
                float x0 = p[half * 8 + 2 * j];
                float x1 = p[half * 8 + 2 * j + 1];
                uint_t u0 = __float_as_uint(x0), u1 = __float_as_uint(x1);
                Ah.i4[j] = PKHI16(u1, u0);
                float l0 = x0 - __uint_as_float(u0 & 0xFFFF0000u);
                float l1 = x1 - __uint_as_float(u1 & 0xFFFF0000u);
                Al.i4[j] = PKHI16(__float_as_uint(l1), __float_as_uint(l0));
            }
            const bf16x8 Vb = half ? cv1 : cv0;
            acc = __builtin_amdgcn_mfma_f32_32x32x16_bf16(Ah.v, Vb, acc, 0, 0, 0);
            acc = __builtin_amdgcn_mfma_f32_32x32x16_bf16(Al.v, Vb, acc, 0, 0, 0);
        }
    }

    #pragma unroll
    for (int j = 0; j < 16; ++j) racc[w][l][j] = acc[j];
    rden[w][l] = den;
    __syncthreads();

    const int q = tid >> 4, d = tid & 15;
    const int rl2 = (q >> 2) & 1;
    const int jj  = (q >> 3) * 4 + (q & 3);
    float sum = 0.f, dn = 0.f;
    #pragma unroll
    for (int ww = 0; ww < 8; ++ww) {
        sum += racc[ww][rl2 * 32 + d][jj] + racc[ww][rl2 * 32 + 16 + d][jj];
        dn  += rden[ww][q] + rden[ww][q + 32];
    }
    float* AOp = ks ? AO1 : AO0;
    AOp[(qbase + q) * 64 + h * 16 + d] = sum;
    if (d == 0) (ks ? DN1 : DN0)[h * PIX + qbase + q] = dn;
}

// ---------------- K4: partial combine + output projection ----------------
__global__ __launch_bounds__(256)
void k_proj(const float* __restrict__ AO0, const float* __restrict__ AO1,
            const float* __restrict__ DN0, const float* __restrict__ DN1,
            const float* __restrict__ w_out, float* __restrict__ out)
{
    __shared__ float as2[16 * 68];
    __shared__ float wo[64 * 68];
    __shared__ float rdn[64];
    const int tid = threadIdx.x;
    const int pbase = blockIdx.x * 16;

    if (tid < 64) {
        int h = tid >> 4, pl = tid & 15;
        rdn[tid] = 1.0f / (DN0[h * PIX + pbase + pl] + DN1[h * PIX + pbase + pl]);
    }
    for (int idx = tid; idx < 4096; idx += 256) {
        int o = idx >> 6, c = idx & 63;
        wo[o * 68 + c] = w_out[idx];
    }
    __syncthreads();
    for (int idx = tid; idx < 1024; idx += 256) {
        int pl = idx >> 6, i = idx & 63;
        float s = AO0[(pbase + pl) * 64 + i] + AO1[(pbase + pl) * 64 + i];
        as2[pl * 68 + i] = s * rdn[(i >> 4) * 16 + pl];
    }
    __syncthreads();

    const int pl = tid & 15;
    const int og = tid >> 4;
    float a0 = 0.f, a1 = 0.f, a2 = 0.f, a3 = 0.f;
    for (int c = 0; c < 64; c += 4) {
        const float4 xv = *(const float4*)&as2[pl * 68 + c];
        const float4 w0 = *(const float4*)&wo[(og * 4 + 0) * 68 + c];
        const float4 w1 = *(const float4*)&wo[(og * 4 + 1) * 68 + c];
        const float4 w2 = *(const float4*)&wo[(og * 4 + 2) * 68 + c];
        const float4 w3 = *(const float4*)&wo[(og * 4 + 3) * 68 + c];
        a0 = fmaf(xv.x, w0.x, fmaf(xv.y, w0.y, fmaf(xv.z, w0.z, fmaf(xv.w, w0.w, a0))));
        a1 = fmaf(xv.x, w1.x, fmaf(xv.y, w1.y, fmaf(xv.z, w1.z, fmaf(xv.w, w1.w, a1))));
        a2 = fmaf(xv.x, w2.x, fmaf(xv.y, w2.y, fmaf(xv.z, w2.z, fmaf(xv.w, w2.w, a2))));
        a3 = fmaf(xv.x, w3.x, fmaf(xv.y, w3.y, fmaf(xv.z, w3.z, fmaf(xv.w, w3.w, a3))));
    }
    out[(og * 4 + 0) * PIX + pbase + pl] = a0;
    out[(og * 4 + 1) * PIX + pbase + pl] = a1;
    out[(og * 4 + 2) * PIX + pbase + pl] = a2;
    out[(og * 4 + 3) * PIX + pbase + pl] = a3;
}

extern "C" void kernel_launch(void* const* d_in, const int* in_sizes, int n_in,
                              void* d_out, int out_size, void* d_ws, size_t ws_size,
                              hipStream_t stream)
{
    const float* x     = (const float*)d_in[0];
    const float* w_qkv = (const float*)d_in[1];
    const float* w_out = (const float*)d_in[2];
    const float* ln_w  = (const float*)d_in[3];
    float* out = (float*)d_out;
    float* ws  = (float*)d_ws;

    float* qkvB = ws;
    float* AO0  = ws + OFF_AO0;
    float* AO1  = ws + OFF_AO1;
    float* DN0  = ws + OFF_DN0;
    float* DN1  = ws + OFF_DN1;
    ushort_t* XH = (ushort_t*)(ws + OFF_AO0);   // alias: consumed before attn writes AO0
    ushort_t* XL = (ushort_t*)(ws + OFF_AO1);
    ushort_t* U  = (ushort_t*)(ws + OFF_USHORT);
    ushort_t* QH = U + U_QH;
    ushort_t* QL = U + U_QL;
    ushort_t* KF = U + U_KF;
    ushort_t* VF = U + U_VF;

    k_norm    <<<dim3(64),   dim3(256), 0, stream>>>(x, ln_w, XH, XL);
    k_qkv     <<<dim3(192),  dim3(256), 0, stream>>>(w_qkv, XH, XL, qkvB, QH, QL);
    k_prep_kv <<<dim3(4608), dim3(256), 0, stream>>>(qkvB, KF, VF);
    k_attn    <<<dim3(1024), dim3(512), 0, stream>>>(QH, QL, KF, VF, AO0, AO1, DN0, DN1);
    k_proj    <<<dim3(256),  dim3(256), 0, stream>>>(AO0, AO1, DN0, DN1, w_out, out);
}

// Round 6
// 113.262 us; speedup vs baseline: 2.3345x; 1.0434x over previous
//
#include <hip/hip_runtime.h>
#include <math.h>

#define PIX 4096
typedef unsigned short ushort_t;
typedef unsigned int uint_t;
typedef __attribute__((ext_vector_type(8))) short bf16x8;
typedef __attribute__((ext_vector_type(16))) float f32x16;

// ---- ws layout (floats) ----
//   qkvB  [128][4096]        @ 0         (k ch 0..63, v ch 64..127)
//   APart [8ks][4h][4096][17]@ 524288    (cols 0-15 = PV partial, col16 = den partial)
// ushort region @ float offset 2752512:
//   QH [4][4096][16] @0   QL @262144
//   KF [4][288][1024] @524288            (per chunk: 512 hi + 512 lo, lane-frag order)
//   VF [4][288][512]  @1703936           (per chunk: 2 halves x 256, hi only, frag order)
#define OFF_APART 524288
#define OFF_USHORT 2752512
#define U_QH 0
#define U_QL 262144
#define U_KF 524288
#define U_VF 1703936

#define QSCALE 0.36067376022224087f   // 0.25 * log2(e)

#if defined(__has_builtin)
#if __has_builtin(__builtin_amdgcn_exp2f)
#define EXP2F(x) __builtin_amdgcn_exp2f(x)
#endif
#if __has_builtin(__builtin_amdgcn_perm)
#define PKHI16(u1, u0) __builtin_amdgcn_perm((u1), (u0), 0x07060302u)
#endif
#endif
#ifndef EXP2F
#define EXP2F(x) exp2f(x)
#endif
#ifndef PKHI16
#define PKHI16(u1, u0) (((u0) >> 16) | ((u1) & 0xFFFF0000u))
#endif

__device__ __forceinline__ void split_trunc(float x, ushort_t& hb, ushort_t& lb) {
    uint_t u = __float_as_uint(x);
    uint_t t = u & 0xFFFF0000u;
    float lo = x - __uint_as_float(t);
    hb = (ushort_t)(u >> 16);
    lb = (ushort_t)(__float_as_uint(lo) >> 16);
}

__device__ __forceinline__ void split8(const float* v, bf16x8& H, bf16x8& L) {
    union { uint_t u[4]; bf16x8 b; } hh, ll;
    #pragma unroll
    for (int j = 0; j < 4; ++j) {
        uint_t u0 = __float_as_uint(v[2 * j]), u1 = __float_as_uint(v[2 * j + 1]);
        hh.u[j] = PKHI16(u1, u0);
        float l0 = v[2 * j]     - __uint_as_float(u0 & 0xFFFF0000u);
        float l1 = v[2 * j + 1] - __uint_as_float(u1 & 0xFFFF0000u);
        ll.u[j] = PKHI16(__float_as_uint(l1), __float_as_uint(l0));
    }
    H = hh.b; L = ll.b;
}

// ---------------- K1: fused norm + qkv MFMA projection ----------------
// grid 256 (px-group = bid>>1 of 32 px, o-half = bid&1), block 256 (4 waves; 3 compute)
__global__ __launch_bounds__(256)
void k_nq(const float* __restrict__ x, const float* __restrict__ w_qkv,
          const float* __restrict__ ln_w, float* __restrict__ qkvB,
          ushort_t* __restrict__ QH, ushort_t* __restrict__ QL)
{
    __shared__ float xs[64 * 32];
    __shared__ float red[2][8][32];
    __shared__ float rstd_s[32];
    __shared__ float lw[64];
    __shared__ ushort_t xh[32 * 64];
    __shared__ ushort_t xl[32 * 64];

    const int tid = threadIdx.x;
    const int px = tid & 31, cg = tid >> 5;
    const int pbase = ((int)blockIdx.x >> 1) * 32;
    const int ohalf = blockIdx.x & 1;

    if (tid < 64) lw[tid] = ln_w[tid];
    float s = 0.f, s2 = 0.f;
    #pragma unroll
    for (int cl = 0; cl < 8; ++cl) {
        int c = cg * 8 + cl;
        float v = x[c * PIX + pbase + px];
        xs[c * 32 + px] = v;
        s += v; s2 = fmaf(v, v, s2);
    }
    red[0][cg][px] = s; red[1][cg][px] = s2;
    __syncthreads();
    if (tid < 32) {
        float a = 0.f, b = 0.f;
        #pragma unroll
        for (int gidx = 0; gidx < 8; ++gidx) { a += red[0][gidx][tid]; b += red[1][gidx][tid]; }
        float mean = a * 0.015625f;
        float var  = fmaf(-mean, mean, b * 0.015625f);
        rstd_s[tid] = 1.0f / sqrtf(var + 1e-5f);
    }
    __syncthreads();
    {
        float vals[8];
        const float r = rstd_s[px];
        #pragma unroll
        for (int cl = 0; cl < 8; ++cl) {
            int c = cg * 8 + cl;
            vals[cl] = xs[c * 32 + px] * r * lw[c];
        }
        bf16x8 H, L; split8(vals, H, L);
        const int g = cg ^ (px & 7);
        *(bf16x8*)&xh[px * 64 + g * 8] = H;
        *(bf16x8*)&xl[px * 64 + g * 8] = L;
    }
    __syncthreads();

    const int w = tid >> 6;
    if (w >= 3) return;
    const int l = tid & 63, col = l & 31, rl = l >> 5;
    const int obase = ohalf * 96 + w * 32;

    bf16x8 wh[4], wl[4], xhf[4], xlf[4];
    const float* wrow = w_qkv + (obase + col) * 64;
    #pragma unroll
    for (int s4 = 0; s4 < 4; ++s4) {
        float tmp[8];
        *(float4*)&tmp[0] = *(const float4*)&wrow[s4 * 16 + rl * 8];
        *(float4*)&tmp[4] = *(const float4*)&wrow[s4 * 16 + rl * 8 + 4];
        split8(tmp, wh[s4], wl[s4]);
        const int g = (s4 * 2 + rl) ^ (col & 7);
        xhf[s4] = *(const bf16x8*)&xh[col * 64 + g * 8];
        xlf[s4] = *(const bf16x8*)&xl[col * 64 + g * 8];
    }
    f32x16 acc = {0,0,0,0,0,0,0,0,0,0,0,0,0,0,0,0};
    #pragma unroll
    for (int s4 = 0; s4 < 4; ++s4) {
        acc = __builtin_amdgcn_mfma_f32_32x32x16_bf16(wh[s4], xhf[s4], acc, 0, 0, 0);
        acc = __builtin_amdgcn_mfma_f32_32x32x16_bf16(wl[s4], xhf[s4], acc, 0, 0, 0);
        acc = __builtin_amdgcn_mfma_f32_32x32x16_bf16(wh[s4], xlf[s4], acc, 0, 0, 0);
    }
    const int gpx = pbase + col;
    #pragma unroll
    for (int j = 0; j < 16; ++j) {
        const int o = obase + (j & 3) + 8 * (j >> 2) + 4 * rl;
        if (o < 64) {
            float qv = acc[j] * QSCALE;
            ushort_t hb, lb; split_trunc(qv, hb, lb);
            const int a = ((o >> 4) * PIX + gpx) * 16 + (o & 15);
            QH[a] = hb; QL[a] = lb;
        } else {
            qkvB[(o - 64) * PIX + gpx] = acc[j];
        }
    }
}

// ---------------- K2: K (hi/lo) + V (hi, 16-col) unfold-gather ----------------
__global__ __launch_bounds__(256)
void k_prep_kv(const float* __restrict__ qkvB,
               ushort_t* __restrict__ KF, ushort_t* __restrict__ VF)
{
    const int t = blockIdx.x * 256 + threadIdx.x;
    if (t < 589824) {
        int h = t / 147456; int r = t - h * 147456;
        int i = r >> 9; int r2 = r & 511;
        int l = r2 >> 3, j = r2 & 7;
        int col = l & 31, rl = l >> 5;
        int m = i * 32 + col;
        int d = rl * 8 + j;
        int cc = m / 576;  int r3 = m - cc * 576;
        int orr = r3 / 48; int r4 = r3 - orr * 48;
        int oc = r4 >> 2, wg = r4 & 3;
        int row  = wg * 16 + (d >> 3) * 8 + orr - 2;
        int colp = (d & 7) * 8 + oc - 2;
        bool ok = ((unsigned)row < 64u) && ((unsigned)colp < 64u);
        float v = ok ? qkvB[(h * 16 + cc) * PIX + row * 64 + colp] : 0.f;
        ushort_t hb, lb; split_trunc(v, hb, lb);
        int base = (h * 288 + i) * 1024 + l * 8 + j;
        KF[base] = hb; KF[base + 512] = lb;
    } else {
        int t2 = t - 589824;
        int h = t2 / 147456; int r = t2 - h * 147456;
        int i = r >> 9; int r2 = r & 511;
        int half = r2 >> 8; int r3 = r2 & 255;
        int rl = r3 >> 7; int colD = (r3 >> 3) & 15; int j2 = r3 & 7;
        int m = i * 32 + half * 16 + rl * 4 + (j2 & 3) + 8 * (j2 >> 2);
        int d = colD;
        int cc = m / 576;  int r4 = m - cc * 576;
        int orr = r4 / 48; int r5 = r4 - orr * 48;
        int oc = r5 >> 2, wg = r5 & 3;
        int row  = wg * 16 + (d >> 3) * 8 + orr - 2;
        int colp = (d & 7) * 8 + oc - 2;
        bool ok = ((unsigned)row < 64u) && ((unsigned)colp < 64u);
        float v = ok ? qkvB[(64 + h * 16 + cc) * PIX + row * 64 + colp] : 0.f;
        uint_t u = __float_as_uint(v);
        VF[(h * 288 + i) * 512 + half * 256 + (rl * 16 + colD) * 8 + j2] = (ushort_t)(u >> 16);
    }
}

// ---------------- K3: MFMA attention, no LDS, ksplit=8, den-in-MFMA ----------------
// grid 1024 x 256 (4 waves). bid: x=bid&7 (XCD) -> h=x>>1, ks-half=x&1; tile=bid>>3.
__global__ __launch_bounds__(256)
void k_attn(const ushort_t* __restrict__ QH, const ushort_t* __restrict__ QL,
            const ushort_t* __restrict__ KF, const ushort_t* __restrict__ VF,
            float* __restrict__ APart)
{
    const int tid = threadIdx.x;
    const int w   = tid >> 6;
    const int l   = tid & 63;
    const int col = l & 31;
    const int rl  = l >> 5;

    const int bid  = blockIdx.x;
    const int x    = bid & 7;
    const int h    = x >> 1;
    const int tile = bid >> 3;
    const int ks   = (x & 1) * 4 + w;
    const int qbase = tile * 32;

    const bf16x8 qh = *(const bf16x8*)&QH[((h << 12) + qbase + col) * 16 + rl * 8];
    const bf16x8 ql = *(const bf16x8*)&QL[((h << 12) + qbase + col) * 16 + rl * 8];

    f32x16 acc = {0,0,0,0,0,0,0,0,0,0,0,0,0,0,0,0};
    const f32x16 zero = {0,0,0,0,0,0,0,0,0,0,0,0,0,0,0,0};

    // B-fragment constants for lanes col>=16: col==16 -> ones (den column), else zeros
    union { uint_t u[4]; bf16x8 b; } vconst;
    const uint_t cfill = (col == 16) ? 0x3F803F80u : 0u;
    vconst.u[0] = cfill; vconst.u[1] = cfill; vconst.u[2] = cfill; vconst.u[3] = cfill;

    const ushort_t* kb = KF + (h * 288 + ks * 36) * 1024;
    const ushort_t* vb = VF + (h * 288 + ks * 36) * 512;

    bf16x8 kh = *(const bf16x8*)&kb[l * 8];
    bf16x8 kl = *(const bf16x8*)&kb[512 + l * 8];
    bf16x8 v0 = vconst.b, v1 = vconst.b;
    if (col < 16) {
        v0 = *(const bf16x8*)&vb[(rl * 16 + col) * 8];
        v1 = *(const bf16x8*)&vb[256 + (rl * 16 + col) * 8];
    }

    for (int i = 0; i < 36; ++i) {
        const bf16x8 ckh = kh, ckl = kl, cv0 = v0, cv1 = v1;
        if (i < 35) {
            kb += 1024; vb += 512;
            kh = *(const bf16x8*)&kb[l * 8];
            kl = *(const bf16x8*)&kb[512 + l * 8];
            if (col < 16) {
                v0 = *(const bf16x8*)&vb[(rl * 16 + col) * 8];
                v1 = *(const bf16x8*)&vb[256 + (rl * 16 + col) * 8];
            }
        }

        f32x16 S = __builtin_amdgcn_mfma_f32_32x32x16_bf16(ckh, qh, zero, 0, 0, 0);
        S = __builtin_amdgcn_mfma_f32_32x32x16_bf16(ckl, qh, S, 0, 0, 0);
        S = __builtin_amdgcn_mfma_f32_32x32x16_bf16(ckh, ql, S, 0, 0, 0);

        float p[16];
        #pragma unroll
        for (int r = 0; r < 16; ++r) p[r] = EXP2F(S[r]);

        union { uint_t u[4]; bf16x8 b; } A0, A1;
        #pragma unroll
        for (int j = 0; j < 4; ++j) {
            A0.u[j] = PKHI16(__float_as_uint(p[2 * j + 1]), __float_as_uint(p[2 * j]));
            A1.u[j] = PKHI16(__float_as_uint(p[8 + 2 * j + 1]), __float_as_uint(p[8 + 2 * j]));
        }
        acc = __builtin_amdgcn_mfma_f32_32x32x16_bf16(A0.b, cv0, acc, 0, 0, 0);
        acc = __builtin_amdgcn_mfma_f32_32x32x16_bf16(A1.b, cv1, acc, 0, 0, 0);
    }

    if (col <= 16) {
        float* base = APart + ((size_t)(ks * 4 + h) << 12) * 17;
        #pragma unroll
        for (int j = 0; j < 16; ++j) {
            const int q = qbase + (j & 3) + 8 * (j >> 2) + 4 * rl;
            base[q * 17 + col] = acc[j];
        }
    }
}

// ---------------- K4: partial combine + divide + output projection ----------------
// grid 256 (16 px each), block 256
__global__ __launch_bounds__(256)
void k_proj(const float* __restrict__ APart, const float* __restrict__ w_out,
            float* __restrict__ out)
{
    __shared__ float asum[16 * 72];
    __shared__ float wo[64 * 68];
    __shared__ float as2[16 * 68];
    __shared__ float rdn[64];
    const int tid = threadIdx.x;
    const int pbase = blockIdx.x * 16;

    for (int idx = tid; idx < 1088; idx += 256) {
        int q_l = idx / 68; int rem = idx - q_l * 68;
        int h = rem / 17;  int c17 = rem - h * 17;
        float s = 0.f;
        #pragma unroll
        for (int ks = 0; ks < 8; ++ks)
            s += APart[((size_t)((ks * 4 + h) * PIX + pbase + q_l)) * 17 + c17];
        asum[q_l * 72 + h * 17 + c17] = s;
    }
    for (int idx = tid; idx < 4096; idx += 256)
        wo[(idx >> 6) * 68 + (idx & 63)] = w_out[idx];
    __syncthreads();
    if (tid < 64) {
        int h = tid >> 4, px = tid & 15;
        rdn[tid] = 1.0f / asum[px * 72 + h * 17 + 16];
    }
    __syncthreads();
    for (int idx = tid; idx < 1024; idx += 256) {
        int px = idx >> 6, ii = idx & 63;
        int h = ii >> 4, d = ii & 15;
        as2[px * 68 + ii] = asum[px * 72 + h * 17 + d] * rdn[h * 16 + px];
    }
    __syncthreads();

    const int pl = tid & 15;
    const int og = tid >> 4;
    float a0 = 0.f, a1 = 0.f, a2 = 0.f, a3 = 0.f;
    for (int c = 0; c < 64; c += 4) {
        const float4 xv = *(const float4*)&as2[pl * 68 + c];
        const float4 w0 = *(const float4*)&wo[(og * 4 + 0) * 68 + c];
        const float4 w1 = *(const float4*)&wo[(og * 4 + 1) * 68 + c];
        const float4 w2 = *(const float4*)&wo[(og * 4 + 2) * 68 + c];
        const float4 w3 = *(const float4*)&wo[(og * 4 + 3) * 68 + c];
        a0 = fmaf(xv.x, w0.x, fmaf(xv.y, w0.y, fmaf(xv.z, w0.z, fmaf(xv.w, w0.w, a0))));
        a1 = fmaf(xv.x, w1.x, fmaf(xv.y, w1.y, fmaf(xv.z, w1.z, fmaf(xv.w, w1.w, a1))));
        a2 = fmaf(xv.x, w2.x, fmaf(xv.y, w2.y, fmaf(xv.z, w2.z, fmaf(xv.w, w2.w, a2))));
        a3 = fmaf(xv.x, w3.x, fmaf(xv.y, w3.y, fmaf(xv.z, w3.z, fmaf(xv.w, w3.w, a3))));
    }
    out[(og * 4 + 0) * PIX + pbase + pl] = a0;
    out[(og * 4 + 1) * PIX + pbase + pl] = a1;
    out[(og * 4 + 2) * PIX + pbase + pl] = a2;
    out[(og * 4 + 3) * PIX + pbase + pl] = a3;
}

extern "C" void kernel_launch(void* const* d_in, const int* in_sizes, int n_in,
                              void* d_out, int out_size, void* d_ws, size_t ws_size,
                              hipStream_t stream)
{
    const float* x     = (const float*)d_in[0];
    const float* w_qkv = (const float*)d_in[1];
    const float* w_out = (const float*)d_in[2];
    const float* ln_w  = (const float*)d_in[3];
    float* out = (float*)d_out;
    float* ws  = (float*)d_ws;

    float* qkvB  = ws;
    float* APart = ws + OFF_APART;
    ushort_t* U  = (ushort_t*)(ws + OFF_USHORT);
    ushort_t* QH = U + U_QH;
    ushort_t* QL = U + U_QL;
    ushort_t* KF = U + U_KF;
    ushort_t* VF = U + U_VF;

    k_nq      <<<dim3(256),  dim3(256), 0, stream>>>(x, w_qkv, ln_w, qkvB, QH, QL);
    k_prep_kv <<<dim3(4608), dim3(256), 0, stream>>>(qkvB, KF, VF);
    k_attn    <<<dim3(1024), dim3(256), 0, stream>>>(QH, QL, KF, VF, APart);
    k_proj    <<<dim3(256),  dim3(256), 0, stream>>>(APart, w_out, out);
}

// Round 7
// 104.737 us; speedup vs baseline: 2.5245x; 1.0814x over previous
//
#include <hip/hip_runtime.h>
#include <math.h>

#define PIX 4096
typedef unsigned short ushort_t;
typedef unsigned int uint_t;
typedef __attribute__((ext_vector_type(8))) short bf16x8;
typedef __attribute__((ext_vector_type(16))) float f32x16;

// ---- ws layout (floats) ----
//   qkvB  [128][4096]          @ 0         (k ch 0..63, v ch 64..127)
//   APart [8ks][4h][4096][17]  @ 524288    (cols 0-15 = PV partial, col16 = den partial)
// ushort region @ float offset 2752512:
//   QH [4][4096][16] @0   QL @262144
//   KF [4][288][1024] @524288            (per chunk: 512 hi + 512 lo, lane-frag order)
//   VF [4][288][512]  @1703936           (per chunk: 2 halves x 256, hi only, frag order)
#define OFF_APART 524288
#define OFF_USHORT 2752512
#define U_QH 0
#define U_QL 262144
#define U_KF 524288
#define U_VF 1703936

#define QSCALE 0.36067376022224087f   // 0.25 * log2(e)

#if defined(__has_builtin)
#if __has_builtin(__builtin_amdgcn_exp2f)
#define EXP2F(x) __builtin_amdgcn_exp2f(x)
#endif
#if __has_builtin(__builtin_amdgcn_perm)
#define PKHI16(u1, u0) __builtin_amdgcn_perm((u1), (u0), 0x07060302u)
#endif
#endif
#ifndef EXP2F
#define EXP2F(x) exp2f(x)
#endif
#ifndef PKHI16
#define PKHI16(u1, u0) (((u0) >> 16) | ((u1) & 0xFFFF0000u))
#endif

__device__ __forceinline__ void split_trunc(float x, ushort_t& hb, ushort_t& lb) {
    uint_t u = __float_as_uint(x);
    uint_t t = u & 0xFFFF0000u;
    float lo = x - __uint_as_float(t);
    hb = (ushort_t)(u >> 16);
    lb = (ushort_t)(__float_as_uint(lo) >> 16);
}

__device__ __forceinline__ void split8(const float* v, bf16x8& H, bf16x8& L) {
    union { uint_t u[4]; bf16x8 b; } hh, ll;
    #pragma unroll
    for (int j = 0; j < 4; ++j) {
        uint_t u0 = __float_as_uint(v[2 * j]), u1 = __float_as_uint(v[2 * j + 1]);
        hh.u[j] = PKHI16(u1, u0);
        float l0 = v[2 * j]     - __uint_as_float(u0 & 0xFFFF0000u);
        float l1 = v[2 * j + 1] - __uint_as_float(u1 & 0xFFFF0000u);
        ll.u[j] = PKHI16(__float_as_uint(l1), __float_as_uint(l0));
    }
    H = hh.b; L = ll.b;
}

// ---------------- K1: fused norm + qkv MFMA projection (unchanged, verified) ----------------
__global__ __launch_bounds__(256)
void k_nq(const float* __restrict__ x, const float* __restrict__ w_qkv,
          const float* __restrict__ ln_w, float* __restrict__ qkvB,
          ushort_t* __restrict__ QH, ushort_t* __restrict__ QL)
{
    __shared__ float xs[64 * 32];
    __shared__ float red[2][8][32];
    __shared__ float rstd_s[32];
    __shared__ float lw[64];
    __shared__ ushort_t xh[32 * 64];
    __shared__ ushort_t xl[32 * 64];

    const int tid = threadIdx.x;
    const int px = tid & 31, cg = tid >> 5;
    const int pbase = ((int)blockIdx.x >> 1) * 32;
    const int ohalf = blockIdx.x & 1;

    if (tid < 64) lw[tid] = ln_w[tid];
    float s = 0.f, s2 = 0.f;
    #pragma unroll
    for (int cl = 0; cl < 8; ++cl) {
        int c = cg * 8 + cl;
        float v = x[c * PIX + pbase + px];
        xs[c * 32 + px] = v;
        s += v; s2 = fmaf(v, v, s2);
    }
    red[0][cg][px] = s; red[1][cg][px] = s2;
    __syncthreads();
    if (tid < 32) {
        float a = 0.f, b = 0.f;
        #pragma unroll
        for (int gidx = 0; gidx < 8; ++gidx) { a += red[0][gidx][tid]; b += red[1][gidx][tid]; }
        float mean = a * 0.015625f;
        float var  = fmaf(-mean, mean, b * 0.015625f);
        rstd_s[tid] = 1.0f / sqrtf(var + 1e-5f);
    }
    __syncthreads();
    {
        float vals[8];
        const float r = rstd_s[px];
        #pragma unroll
        for (int cl = 0; cl < 8; ++cl) {
            int c = cg * 8 + cl;
            vals[cl] = xs[c * 32 + px] * r * lw[c];
        }
        bf16x8 H, L; split8(vals, H, L);
        const int g = cg ^ (px & 7);
        *(bf16x8*)&xh[px * 64 + g * 8] = H;
        *(bf16x8*)&xl[px * 64 + g * 8] = L;
    }
    __syncthreads();

    const int w = tid >> 6;
    if (w >= 3) return;
    const int l = tid & 63, col = l & 31, rl = l >> 5;
    const int obase = ohalf * 96 + w * 32;

    bf16x8 wh[4], wl[4], xhf[4], xlf[4];
    const float* wrow = w_qkv + (obase + col) * 64;
    #pragma unroll
    for (int s4 = 0; s4 < 4; ++s4) {
        float tmp[8];
        *(float4*)&tmp[0] = *(const float4*)&wrow[s4 * 16 + rl * 8];
        *(float4*)&tmp[4] = *(const float4*)&wrow[s4 * 16 + rl * 8 + 4];
        split8(tmp, wh[s4], wl[s4]);
        const int g = (s4 * 2 + rl) ^ (col & 7);
        xhf[s4] = *(const bf16x8*)&xh[col * 64 + g * 8];
        xlf[s4] = *(const bf16x8*)&xl[col * 64 + g * 8];
    }
    f32x16 acc = {0,0,0,0,0,0,0,0,0,0,0,0,0,0,0,0};
    #pragma unroll
    for (int s4 = 0; s4 < 4; ++s4) {
        acc = __builtin_amdgcn_mfma_f32_32x32x16_bf16(wh[s4], xhf[s4], acc, 0, 0, 0);
        acc = __builtin_amdgcn_mfma_f32_32x32x16_bf16(wl[s4], xhf[s4], acc, 0, 0, 0);
        acc = __builtin_amdgcn_mfma_f32_32x32x16_bf16(wh[s4], xlf[s4], acc, 0, 0, 0);
    }
    const int gpx = pbase + col;
    #pragma unroll
    for (int j = 0; j < 16; ++j) {
        const int o = obase + (j & 3) + 8 * (j >> 2) + 4 * rl;
        if (o < 64) {
            float qv = acc[j] * QSCALE;
            ushort_t hb, lb; split_trunc(qv, hb, lb);
            const int a = ((o >> 4) * PIX + gpx) * 16 + (o & 15);
            QH[a] = hb; QL[a] = lb;
        } else {
            qkvB[(o - 64) * PIX + gpx] = acc[j];
        }
    }
}

// ---------------- K2: K (hi/lo) + V (hi) unfold-gather, 8 elems/thread ----------------
// grid 576 x 256: blocks [0,288) = K rows, [288,576) = V rows
__global__ __launch_bounds__(256)
void k_prep_kv(const float* __restrict__ qkvB,
               ushort_t* __restrict__ KF, ushort_t* __restrict__ VF)
{
    const int bid = blockIdx.x;
    const int tid = threadIdx.x;
    if (bid < 288) {
        // K: thread per (h, chunk i, lane l); 8 d-elems (j=0..7), same source row
        const int t = bid * 256 + tid;          // < 73728
        const int h = t / 18432; int r = t - h * 18432;
        const int i = r >> 6;   const int l = r & 63;
        const int col = l & 31, rl = l >> 5;
        const int m = i * 32 + col;
        const int cc = m / 576;  const int r3 = m - cc * 576;
        const int orr = r3 / 48; const int r4 = r3 - orr * 48;
        const int oc = r4 >> 2, wg = r4 & 3;
        const int row = wg * 16 + rl * 8 + orr - 2;   // d>>3 == rl for all j
        const bool rowOk = (unsigned)row < 64u;
        const float* src = qkvB + (h * 16 + cc) * PIX + row * 64 + (oc - 2);
        float vals[8];
        #pragma unroll
        for (int j = 0; j < 8; ++j) {
            const int colp = j * 8 + oc - 2;
            vals[j] = (rowOk && (unsigned)colp < 64u) ? src[j * 8] : 0.f;
        }
        bf16x8 H, L; split8(vals, H, L);
        const int base = (h * 288 + i) * 1024 + l * 8;
        *(bf16x8*)&KF[base]       = H;
        *(bf16x8*)&KF[base + 512] = L;
    } else {
        // V: thread per (h, chunk i, half, rl, colD); 8 m-elems (j2=0..7), d fixed
        const int t = (bid - 288) * 256 + tid;  // < 73728
        const int h = t / 18432; int r = t - h * 18432;
        const int i = r >> 6;   const int r2 = r & 63;
        const int half = r2 >> 5; const int rl = (r2 >> 4) & 1; const int colD = r2 & 15;
        const int d = colD;
        const int vcolp = (d & 7) * 8 - 2;      // + oc
        const int rbase = (d >> 3) * 8 - 2;     // + wg*16 + orr
        const float* srcp = qkvB + (64 + h * 16) * PIX;
        union { ushort_t us[8]; bf16x8 b; } o8;
        #pragma unroll
        for (int j2 = 0; j2 < 8; ++j2) {
            const int m = i * 32 + half * 16 + rl * 4 + (j2 & 3) + 8 * (j2 >> 2);
            const int cc = m / 576;  const int r3 = m - cc * 576;
            const int orr = r3 / 48; const int r4 = r3 - orr * 48;
            const int oc = r4 >> 2, wg = r4 & 3;
            const int row  = wg * 16 + rbase + orr;
            const int colp = vcolp + oc;
            const bool ok = ((unsigned)row < 64u) && ((unsigned)colp < 64u);
            const float v = ok ? srcp[cc * PIX + row * 64 + colp] : 0.f;
            o8.us[j2] = (ushort_t)(__float_as_uint(v) >> 16);
        }
        *(bf16x8*)&VF[(h * 288 + i) * 512 + half * 256 + (rl * 16 + colD) * 8] = o8.b;
    }
}

// ---------------- K3: MFMA attention, 64 q/wave, no LDS, den-in-MFMA ----------------
// grid 256 x 512 (8 waves = 8 key-splits). bid: x=bid&7 -> h=x>>1, tile LSB=x&1.
__global__ __launch_bounds__(512)
void k_attn(const ushort_t* __restrict__ QH, const ushort_t* __restrict__ QL,
            const ushort_t* __restrict__ KF, const ushort_t* __restrict__ VF,
            float* __restrict__ APart)
{
    const int tid = threadIdx.x;
    const int w   = tid >> 6;       // ks = w
    const int l   = tid & 63;
    const int col = l & 31;
    const int rl  = l >> 5;

    const int bid  = blockIdx.x;
    const int x    = bid & 7;
    const int h    = x >> 1;
    const int tile = ((bid >> 3) << 1) | (x & 1);   // 0..63, 64 queries each
    const int qbase = tile * 64;

    const ushort_t* Qb = QH + ((h << 12) + qbase + col) * 16 + rl * 8;
    const ushort_t* Qb2 = QL + ((h << 12) + qbase + col) * 16 + rl * 8;
    const bf16x8 qh0 = *(const bf16x8*)&Qb[0];
    const bf16x8 qh1 = *(const bf16x8*)&Qb[512];    // +32 pixels * 16
    const bf16x8 ql0 = *(const bf16x8*)&Qb2[0];
    const bf16x8 ql1 = *(const bf16x8*)&Qb2[512];

    f32x16 acc0 = {0,0,0,0,0,0,0,0,0,0,0,0,0,0,0,0};
    f32x16 acc1 = {0,0,0,0,0,0,0,0,0,0,0,0,0,0,0,0};
    const f32x16 zero = {0,0,0,0,0,0,0,0,0,0,0,0,0,0,0,0};

    union { uint_t u[4]; bf16x8 b; } vconst;
    const uint_t cfill = (col == 16) ? 0x3F803F80u : 0u;
    vconst.u[0] = cfill; vconst.u[1] = cfill; vconst.u[2] = cfill; vconst.u[3] = cfill;

    const ushort_t* kb = KF + (h * 288 + w * 36) * 1024;
    const ushort_t* vb = VF + (h * 288 + w * 36) * 512;

    bf16x8 kh = *(const bf16x8*)&kb[l * 8];
    bf16x8 kl = *(const bf16x8*)&kb[512 + l * 8];
    bf16x8 v0 = vconst.b, v1 = vconst.b;
    if (col < 16) {
        v0 = *(const bf16x8*)&vb[(rl * 16 + col) * 8];
        v1 = *(const bf16x8*)&vb[256 + (rl * 16 + col) * 8];
    }

    for (int i = 0; i < 36; ++i) {
        const bf16x8 ckh = kh, ckl = kl, cv0 = v0, cv1 = v1;
        if (i < 35) {
            kb += 1024; vb += 512;
            kh = *(const bf16x8*)&kb[l * 8];
            kl = *(const bf16x8*)&kb[512 + l * 8];
            if (col < 16) {
                v0 = *(const bf16x8*)&vb[(rl * 16 + col) * 8];
                v1 = *(const bf16x8*)&vb[256 + (rl * 16 + col) * 8];
            }
        }

        f32x16 S0 = __builtin_amdgcn_mfma_f32_32x32x16_bf16(ckh, qh0, zero, 0, 0, 0);
        S0 = __builtin_amdgcn_mfma_f32_32x32x16_bf16(ckl, qh0, S0, 0, 0, 0);
        S0 = __builtin_amdgcn_mfma_f32_32x32x16_bf16(ckh, ql0, S0, 0, 0, 0);
        f32x16 S1 = __builtin_amdgcn_mfma_f32_32x32x16_bf16(ckh, qh1, zero, 0, 0, 0);
        S1 = __builtin_amdgcn_mfma_f32_32x32x16_bf16(ckl, qh1, S1, 0, 0, 0);
        S1 = __builtin_amdgcn_mfma_f32_32x32x16_bf16(ckh, ql1, S1, 0, 0, 0);

        {
            float p[16];
            #pragma unroll
            for (int r = 0; r < 16; ++r) p[r] = EXP2F(S0[r]);
            union { uint_t u[4]; bf16x8 b; } A0, A1;
            #pragma unroll
            for (int j = 0; j < 4; ++j) {
                A0.u[j] = PKHI16(__float_as_uint(p[2 * j + 1]), __float_as_uint(p[2 * j]));
                A1.u[j] = PKHI16(__float_as_uint(p[8 + 2 * j + 1]), __float_as_uint(p[8 + 2 * j]));
            }
            acc0 = __builtin_amdgcn_mfma_f32_32x32x16_bf16(A0.b, cv0, acc0, 0, 0, 0);
            acc0 = __builtin_amdgcn_mfma_f32_32x32x16_bf16(A1.b, cv1, acc0, 0, 0, 0);
        }
        {
            float p[16];
            #pragma unroll
            for (int r = 0; r < 16; ++r) p[r] = EXP2F(S1[r]);
            union { uint_t u[4]; bf16x8 b; } A0, A1;
            #pragma unroll
            for (int j = 0; j < 4; ++j) {
                A0.u[j] = PKHI16(__float_as_uint(p[2 * j + 1]), __float_as_uint(p[2 * j]));
                A1.u[j] = PKHI16(__float_as_uint(p[8 + 2 * j + 1]), __float_as_uint(p[8 + 2 * j]));
            }
            acc1 = __builtin_amdgcn_mfma_f32_32x32x16_bf16(A0.b, cv0, acc1, 0, 0, 0);
            acc1 = __builtin_amdgcn_mfma_f32_32x32x16_bf16(A1.b, cv1, acc1, 0, 0, 0);
        }
    }

    if (col <= 16) {
        float* base = APart + ((size_t)(w * 4 + h) << 12) * 17;
        #pragma unroll
        for (int j = 0; j < 16; ++j) {
            const int q = qbase + (j & 3) + 8 * (j >> 2) + 4 * rl;
            base[q * 17 + col]        = acc0[j];
            base[(q + 32) * 17 + col] = acc1[j];
        }
    }
}

// ---------------- K4: partial combine + divide + output projection ----------------
__global__ __launch_bounds__(256)
void k_proj(const float* __restrict__ APart, const float* __restrict__ w_out,
            float* __restrict__ out)
{
    __shared__ float asum[16 * 72];
    __shared__ float wo[64 * 68];
    __shared__ float as2[16 * 68];
    __shared__ float rdn[64];
    const int tid = threadIdx.x;
    const int pbase = blockIdx.x * 16;

    for (int idx = tid; idx < 1088; idx += 256) {
        int q_l = idx / 68; int rem = idx - q_l * 68;
        int h = rem / 17;  int c17 = rem - h * 17;
        float s = 0.f;
        #pragma unroll
        for (int ks = 0; ks < 8; ++ks)
            s += APart[((size_t)((ks * 4 + h) * PIX + pbase + q_l)) * 17 + c17];
        asum[q_l * 72 + h * 17 + c17] = s;
    }
    for (int idx = tid; idx < 4096; idx += 256)
        wo[(idx >> 6) * 68 + (idx & 63)] = w_out[idx];
    __syncthreads();
    if (tid < 64) {
        int h = tid >> 4, px = tid & 15;
        rdn[tid] = 1.0f / asum[px * 72 + h * 17 + 16];
    }
    __syncthreads();
    for (int idx = tid; idx < 1024; idx += 256) {
        int px = idx >> 6, ii = idx & 63;
        int h = ii >> 4, d = ii & 15;
        as2[px * 68 + ii] = asum[px * 72 + h * 17 + d] * rdn[h * 16 + px];
    }
    __syncthreads();

    const int pl = tid & 15;
    const int og = tid >> 4;
    float a0 = 0.f, a1 = 0.f, a2 = 0.f, a3 = 0.f;
    for (int c = 0; c < 64; c += 4) {
        const float4 xv = *(const float4*)&as2[pl * 68 + c];
        const float4 w0 = *(const float4*)&wo[(og * 4 + 0) * 68 + c];
        const float4 w1 = *(const float4*)&wo[(og * 4 + 1) * 68 + c];
        const float4 w2 = *(const float4*)&wo[(og * 4 + 2) * 68 + c];
        const float4 w3 = *(const float4*)&wo[(og * 4 + 3) * 68 + c];
        a0 = fmaf(xv.x, w0.x, fmaf(xv.y, w0.y, fmaf(xv.z, w0.z, fmaf(xv.w, w0.w, a0))));
        a1 = fmaf(xv.x, w1.x, fmaf(xv.y, w1.y, fmaf(xv.z, w1.z, fmaf(xv.w, w1.w, a1))));
        a2 = fmaf(xv.x, w2.x, fmaf(xv.y, w2.y, fmaf(xv.z, w2.z, fmaf(xv.w, w2.w, a2))));
        a3 = fmaf(xv.x, w3.x, fmaf(xv.y, w3.y, fmaf(xv.z, w3.z, fmaf(xv.w, w3.w, a3))));
    }
    out[(og * 4 + 0) * PIX + pbase + pl] = a0;
    out[(og * 4 + 1) * PIX + pbase + pl] = a1;
    out[(og * 4 + 2) * PIX + pbase + pl] = a2;
    out[(og * 4 + 3) * PIX + pbase + pl] = a3;
}

extern "C" void kernel_launch(void* const* d_in, const int* in_sizes, int n_in,
                              void* d_out, int out_size, void* d_ws, size_t ws_size,
                              hipStream_t stream)
{
    const float* x     = (const float*)d_in[0];
    const float* w_qkv = (const float*)d_in[1];
    const float* w_out = (const float*)d_in[2];
    const float* ln_w  = (const float*)d_in[3];
    float* out = (float*)d_out;
    float* ws  = (float*)d_ws;

    float* qkvB  = ws;
    float* APart = ws + OFF_APART;
    ushort_t* U  = (ushort_t*)(ws + OFF_USHORT);
    ushort_t* QH = U + U_QH;
    ushort_t* QL = U + U_QL;
    ushort_t* KF = U + U_KF;
    ushort_t* VF = U + U_VF;

    k_nq      <<<dim3(256), dim3(256), 0, stream>>>(x, w_qkv, ln_w, qkvB, QH, QL);
    k_prep_kv <<<dim3(576), dim3(256), 0, stream>>>(qkvB, KF, VF);
    k_attn    <<<dim3(256), dim3(512), 0, stream>>>(QH, QL, KF, VF, APart);
    k_proj    <<<dim3(256), dim3(256), 0, stream>>>(APart, w_out, out);
}